// Round 8
// baseline (1144.914 us; speedup 1.0000x reference)
//
#include <hip/hip_runtime.h>
#include <math.h>

#define NB 16
#define NR 64
#define NCOL 64
#define ND 2048
#define DIM 512

typedef __attribute__((ext_vector_type(4))) float f32x4;
typedef __attribute__((ext_vector_type(8))) short bf16x8;
typedef __attribute__((ext_vector_type(8))) unsigned short us8;

// ---------------- workspace layout (float offsets) ----------------
#define OFF_RHNUM  0L
#define OFF_CHNUM  1024L
#define OFF_DCNUM  2048L
#define OFF_RHW    34816L
#define OFF_CHW    35840L
#define OFF_QROW   36864L
#define OFF_QCOL   45056L
#define OFF_PRER   53248L
#define OFF_PREC   577536L
#define OFF_INFORC 1101824L   // ihiT/iloT bf16 info planes [b][512][128] (4 MB)
#define OFF_BITS   2150400L
#define OFF_DCS    4247552L   // dhi/dlo row-major planes
#define OFF_PROJ   21024768L  // thi/tlo transposed dcs planes, then phi/plo proj planes
#define WS_FLOATS  37801984L  // 151.2 MB
// whi/wlo live in the out-dc slice (dead mid-iteration)

// RNE fp32 -> bf16 split: v ~= hi + lo, both bf16
__device__ inline void bsplit(float v, unsigned short& h, unsigned short& l) {
    unsigned uv = __float_as_uint(v);
    unsigned hb = (uv + 0x7FFFu + ((uv >> 16) & 1u)) >> 16;
    h = (unsigned short)hb;
    float lo = v - __uint_as_float(hb << 16);
    unsigned lv = __float_as_uint(lo);
    l = (unsigned short)((lv + 0x7FFFu + ((lv >> 16) & 1u)) >> 16);
}

// spread 8 bits to every 4th position of a 32-bit word
__device__ inline unsigned spread4(unsigned x) {
    x = (x | (x << 12)) & 0x000F000Fu;
    x = (x | (x << 6))  & 0x03030303u;
    x = (x | (x << 3))  & 0x11111111u;
    return x;
}

// shared MFMA phase: 2 ks x (4x4) x 2 products (A exact, B hi+lo)
__device__ inline void mfma_phase2(const unsigned short* Aexp, const unsigned short* Bhi,
                                   const unsigned short* Blo, int wm, int wn, int lane,
                                   f32x4 acc[4][4])
{
    #pragma unroll
    for (int ks = 0; ks < 2; ks++) {
        bf16x8 af[4], bh[4], bl[4];
        #pragma unroll
        for (int i = 0; i < 4; i++) {
            int rr = wm * 64 + i * 16 + (lane & 15);
            int cc = (ks * 4 + (lane >> 4)) ^ (rr & 7);
            af[i] = *(const bf16x8*)((const char*)Aexp + rr * 128 + cc * 16);
            int nn = wn * 64 + i * 16 + (lane & 15);
            int c2 = (ks * 4 + (lane >> 4)) ^ (nn & 7);
            bh[i] = *(const bf16x8*)((const char*)Bhi + nn * 128 + c2 * 16);
            bl[i] = *(const bf16x8*)((const char*)Blo + nn * 128 + c2 * 16);
        }
        #pragma unroll
        for (int mi = 0; mi < 4; mi++)
            #pragma unroll
            for (int ni = 0; ni < 4; ni++) {
                acc[mi][ni] = __builtin_amdgcn_mfma_f32_16x16x32_bf16(af[mi], bh[ni], acc[mi][ni], 0, 0, 0);
                acc[mi][ni] = __builtin_amdgcn_mfma_f32_16x16x32_bf16(af[mi], bl[ni], acc[mi][ni], 0, 0, 0);
            }
    }
}

// ============ gate for rh/ch rows ============
__global__ __launch_bounds__(256) void k_gate_rc(
    const float* __restrict__ rh, const float* __restrict__ ch,
    const int* __restrict__ rm, const int* __restrict__ cm,
    const float* __restrict__ wnode,
    float* __restrict__ rh_w, float* __restrict__ ch_w)
{
    int wave = threadIdx.x >> 6, lane = threadIdx.x & 63;
    int idx = blockIdx.x * 4 + wave;   // < 2048
    const float* xrow; float* outw; int mval;
    if (idx < NB * NR) {
        int b = idx >> 6, r = idx & 63;
        xrow = rh + ((long)b * NR + r) * DIM; mval = rm[b * NR + r]; outw = rh_w + b * NR + r;
    } else {
        int tt = idx - NB * NR; int b = tt >> 6, c = tt & 63;
        xrow = ch + ((long)b * NCOL + c) * DIM; mval = cm[b * NCOL + c]; outw = ch_w + b * NCOL + c;
    }
    const float4* px = (const float4*)xrow;
    const float4* pw = (const float4*)wnode;
    float4 xa = px[lane * 2], xb = px[lane * 2 + 1];
    float4 wa = pw[lane * 2], wb = pw[lane * 2 + 1];
    float s = xa.x * wa.x + xa.y * wa.y + xa.z * wa.z + xa.w * wa.w
            + xb.x * wb.x + xb.y * wb.y + xb.z * wb.z + xb.w * wb.w;
    #pragma unroll
    for (int o = 32; o > 0; o >>= 1) s += __shfl_xor(s, o, 64);
    if (lane == 0) {
        float g = 1.f / (1.f + expf(-s));
        *outw = mval ? g : 0.f;
    }
}

// ============ gate+split dc -> dhi/dlo [b][2048][512] AND thi/tlo [b][512][2048] ============
__global__ __launch_bounds__(256) void k_split(
    const float* __restrict__ src, const float* __restrict__ wnode, const int* __restrict__ dmask,
    unsigned short* __restrict__ dhi, unsigned short* __restrict__ dlo,
    unsigned short* __restrict__ thi, unsigned short* __restrict__ tlo)
{
    int b = blockIdx.y, j0 = blockIdx.x * 16;
    __shared__ float X[16 * 512];
    __shared__ float scs[16];
    int t = threadIdx.x;
    int r = t >> 4, u = t & 15;
    const float* row = src + ((long)b * ND + j0 + r) * DIM;
    float part = 0.f;
    #pragma unroll
    for (int i = 0; i < 8; i++) {
        int col = i * 64 + u * 4;
        float4 v = *(const float4*)(row + col);
        float4 w = *(const float4*)(wnode + col);
        part += v.x * w.x + v.y * w.y + v.z * w.z + v.w * w.w;
        *(float4*)&X[r * 512 + (col ^ ((r & 7) * 4))] = v;
    }
    part += __shfl_xor(part, 1, 64);
    part += __shfl_xor(part, 2, 64);
    part += __shfl_xor(part, 4, 64);
    part += __shfl_xor(part, 8, 64);
    if (u == 0) {
        float g = 1.f / (1.f + expf(-part));
        scs[r] = (dmask[(long)b * ND + j0 + r] != 0) ? g : 0.f;
    }
    __syncthreads();
    // row-major planes
    {
        float s = scs[r];
        long ob = ((long)b * ND + j0 + r) * DIM + u * 32;
        #pragma unroll
        for (int g = 0; g < 4; g++) {
            us8 ph, pl;
            #pragma unroll
            for (int e = 0; e < 8; e++) {
                int cc = u * 32 + g * 8 + e;
                float v = X[r * 512 + (cc ^ ((r & 7) * 4))] * s;
                unsigned short hh, ll; bsplit(v, hh, ll);
                ph[e] = hh; pl[e] = ll;
            }
            *(us8*)(dhi + ob + g * 8) = ph;
            *(us8*)(dlo + ob + g * 8) = pl;
        }
    }
    // transposed planes
    #pragma unroll
    for (int h = 0; h < 2; h++) {
        int n = t + h * 256;
        us8 ph0, ph1, pl0, pl1;
        #pragma unroll
        for (int rr = 0; rr < 16; rr++) {
            float v = X[rr * 512 + (n ^ ((rr & 7) * 4))] * scs[rr];
            unsigned short hh, ll; bsplit(v, hh, ll);
            if (rr < 8) { ph0[rr] = hh; pl0[rr] = ll; }
            else        { ph1[rr - 8] = hh; pl1[rr - 8] = ll; }
        }
        long ob = ((long)b * DIM + n) * ND + j0;
        *(us8*)(thi + ob) = ph0; *(us8*)(thi + ob + 8) = ph1;
        *(us8*)(tlo + ob) = pl0; *(us8*)(tlo + ob + 8) = pl1;
    }
}

// ============ split w_sr -> whi/wlo bf16 [512][512] ============
__global__ __launch_bounds__(256) void k_wsplit(
    const float* __restrict__ w, unsigned short* __restrict__ whi, unsigned short* __restrict__ wlo)
{
    long i = ((long)blockIdx.x * 256 + threadIdx.x) * 8;
    float4 a = *(const float4*)(w + i), b4 = *(const float4*)(w + i + 4);
    float v[8] = {a.x, a.y, a.z, a.w, b4.x, b4.y, b4.z, b4.w};
    us8 ph, pl;
    #pragma unroll
    for (int t = 0; t < 8; t++) {
        unsigned short hh, ll; bsplit(v[t], hh, ll);
        ph[t] = hh; pl[t] = ll;
    }
    *(us8*)(whi + i) = ph;
    *(us8*)(wlo + i) = pl;
}

// ============ q projections (once) ============
__global__ __launch_bounds__(256) void k_q(
    const float* __restrict__ q, const float* __restrict__ wrq, const float* __restrict__ wcq,
    float* __restrict__ qrow, float* __restrict__ qcol)
{
    int b = blockIdx.z;
    const float* W = blockIdx.y ? wcq : wrq;
    float* out = blockIdx.y ? qcol : qrow;
    int wave = threadIdx.x >> 6, lane = threadIdx.x & 63;
    int n = blockIdx.x * 4 + wave;
    const float4* qp = (const float4*)(q + (long)b * DIM);
    const float4* wp = (const float4*)(W + (long)n * DIM);
    float4 a0 = qp[lane * 2], a1 = qp[lane * 2 + 1];
    float4 w0 = wp[lane * 2], w1 = wp[lane * 2 + 1];
    float s = a0.x * w0.x + a0.y * w0.y + a0.z * w0.z + a0.w * w0.w
            + a1.x * w1.x + a1.y * w1.y + a1.z * w1.z + a1.w * w1.w;
    #pragma unroll
    for (int o = 32; o > 0; o >>= 1) s += __shfl_xor(s, o, 64);
    if (lane == 0) out[(long)b * DIM + n] = s;
}

// ============ pack same_row bits + partial dc_num: 2 rows/block, deep loads ============
__global__ __launch_bounds__(256) void k_bits(
    const int* __restrict__ sr, const int* __restrict__ sc, const int* __restrict__ dmask,
    unsigned* __restrict__ bits, float* __restrict__ dcnum)
{
    long bi0 = (long)blockIdx.x * 2;         // rows bi0, bi0+1 (same batch: ND even)
    int b = (int)(bi0 >> 11);
    int wave = threadIdx.x >> 6, lane = threadIdx.x & 63;
    const int4* dm4 = (const int4*)(dmask + (long)b * ND);
    // issue all loads up front (independent -> deep in flight)
    int4 vs[2][2], vc[2][2], vd[2];
    #pragma unroll
    for (int h = 0; h < 2; h++) {
        int vidx = wave * 128 + h * 64 + lane;
        vd[h] = dm4[vidx];
        #pragma unroll
        for (int r = 0; r < 2; r++) {
            vs[r][h] = ((const int4*)(sr + (bi0 + r) * ND))[vidx];
            vc[r][h] = ((const int4*)(sc + (bi0 + r) * ND))[vidx];
        }
    }
    int dmi0 = dmask[bi0], dmi1 = dmask[bi0 + 1];
    __shared__ int red[2][4];
    #pragma unroll
    for (int r = 0; r < 2; r++) {
        int dmi = r ? dmi1 : dmi0;
        unsigned* brow = bits + (bi0 + r) * 64;
        int cnt = 0;
        #pragma unroll
        for (int h = 0; h < 2; h++) {
            int4 s4 = vs[r][h], c4 = vc[r][h], d4 = vd[h];
            bool d0 = dmi && d4.x, d1 = dmi && d4.y, d2 = dmi && d4.z, d3 = dmi && d4.w;
            unsigned long long m0 = __ballot(d0 && s4.x);
            unsigned long long m1 = __ballot(d1 && s4.y);
            unsigned long long m2 = __ballot(d2 && s4.z);
            unsigned long long m3 = __ballot(d3 && s4.w);
            unsigned long long n0 = __ballot(d0 && c4.x);
            unsigned long long n1 = __ballot(d1 && c4.y);
            unsigned long long n2 = __ballot(d2 && c4.z);
            unsigned long long n3 = __ballot(d3 && c4.w);
            cnt += __popcll(m0) + __popcll(m1) + __popcll(m2) + __popcll(m3)
                 + __popcll(n0) + __popcll(n1) + __popcll(n2) + __popcll(n3);
            if (lane < 8) {
                unsigned w = spread4((unsigned)(m0 >> (8 * lane)) & 0xFFu)
                           | (spread4((unsigned)(m1 >> (8 * lane)) & 0xFFu) << 1)
                           | (spread4((unsigned)(m2 >> (8 * lane)) & 0xFFu) << 2)
                           | (spread4((unsigned)(m3 >> (8 * lane)) & 0xFFu) << 3);
                brow[wave * 16 + h * 8 + lane] = w;
            }
        }
        if (lane == 0) red[r][wave] = cnt;   // cnt is wave-uniform (ballot popcounts)
    }
    __syncthreads();
    if (threadIdx.x < 2) {
        int s = red[threadIdx.x][0] + red[threadIdx.x][1] + red[threadIdx.x][2] + red[threadIdx.x][3];
        dcnum[bi0 + threadIdx.x] = (float)s;
    }
}

// ============ rh_num / ch_num ============
__global__ __launch_bounds__(256) void k_rcnum(
    const int* __restrict__ rel_rd, const int* __restrict__ rel_cd,
    const int* __restrict__ rm, const int* __restrict__ cm, const int* __restrict__ dmask,
    float* __restrict__ rh_num, float* __restrict__ ch_num)
{
    int wave = threadIdx.x >> 6, lane = threadIdx.x & 63;
    long idx = (long)blockIdx.x * 4 + wave;  // < 2048
    const int* row; int mval; float* out; const int* dmb;
    if (idx < NB * NR) {
        int b = (int)(idx >> 6), r = (int)(idx & 63);
        row = rel_rd + ((long)b * NR + r) * ND; mval = rm[b * NR + r];
        out = rh_num + b * NR + r; dmb = dmask + (long)b * ND;
    } else {
        long tt = idx - NB * NR; int b = (int)(tt >> 6), c = (int)(tt & 63);
        row = rel_cd + ((long)b * NCOL + c) * ND; mval = cm[b * NCOL + c];
        out = ch_num + b * NCOL + c; dmb = dmask + (long)b * ND;
    }
    int cnt = 0;
    for (int rr = 0; rr < 32; rr++) {
        int j = rr * 64 + lane;
        cnt += (row[j] != 0 && dmb[j] != 0) ? 1 : 0;
    }
    #pragma unroll
    for (int o = 32; o > 0; o >>= 1) cnt += __shfl_xor(cnt, o, 64);
    if (lane == 0) {
        float s = mval ? (float)cnt : 0.f;
        *out = (s >= 1.f) ? (s + 1.f) : 1.f;
    }
}

// ============ finalize dc_num ============
__global__ __launch_bounds__(256) void k_dcnum_final(
    const int* __restrict__ rel_rd, const int* __restrict__ rel_cd,
    const int* __restrict__ rm, const int* __restrict__ cm, const int* __restrict__ dmask,
    float* __restrict__ dcnum)
{
    int b = blockIdx.y;
    int j = blockIdx.x * 256 + threadIdx.x;
    const int* rd = rel_rd + (long)b * NR * ND;
    const int* cd = rel_cd + (long)b * NCOL * ND;
    const int* rmb = rm + b * NR;
    const int* cmb = cm + b * NCOL;
    int cnt = 0;
    for (int r = 0; r < NR; r++)  cnt += (rd[(long)r * ND + j] != 0 && rmb[r] != 0) ? 1 : 0;
    for (int c = 0; c < NCOL; c++) cnt += (cd[(long)c * ND + j] != 0 && cmb[c] != 0) ? 1 : 0;
    float add = (dmask[(long)b * ND + j] != 0) ? (float)cnt : 0.f;
    float tv = dcnum[(long)b * ND + j] + add;
    dcnum[(long)b * ND + j] = (tv >= 1.f) ? tv : 1.f;
}

// ============ gemm_info: M=64,N=512,K=512 -> transposed bf16 info planes [b][512][128] ============
__global__ __launch_bounds__(256) void gemm_info(
    const float* __restrict__ A, long sA,
    const float* __restrict__ W,
    unsigned short* __restrict__ ihiT, unsigned short* __restrict__ iloT, int hoff,
    const float* __restrict__ rowscale, float alpha)
{
    int b = blockIdx.z;
    int n0 = blockIdx.x * 64;
    __shared__ float As[32][68], Ws[32][68];
    float acc[4][4] = {};
    int tx = threadIdx.x & 15, ty = threadIdx.x >> 4;
    int lm = threadIdx.x >> 2, lk = (threadIdx.x & 3) * 8;
    const float* Ab = A + (long)b * sA;
    for (int k0 = 0; k0 < DIM; k0 += 32) {
        const float4* pa = (const float4*)(Ab + (long)lm * DIM + k0 + lk);
        float4 va0 = pa[0], va1 = pa[1];
        const float4* pw = (const float4*)(W + (long)(n0 + lm) * DIM + k0 + lk);
        float4 vw0 = pw[0], vw1 = pw[1];
        As[lk + 0][lm] = va0.x; As[lk + 1][lm] = va0.y; As[lk + 2][lm] = va0.z; As[lk + 3][lm] = va0.w;
        As[lk + 4][lm] = va1.x; As[lk + 5][lm] = va1.y; As[lk + 6][lm] = va1.z; As[lk + 7][lm] = va1.w;
        Ws[lk + 0][lm] = vw0.x; Ws[lk + 1][lm] = vw0.y; Ws[lk + 2][lm] = vw0.z; Ws[lk + 3][lm] = vw0.w;
        Ws[lk + 4][lm] = vw1.x; Ws[lk + 5][lm] = vw1.y; Ws[lk + 6][lm] = vw1.z; Ws[lk + 7][lm] = vw1.w;
        __syncthreads();
        #pragma unroll
        for (int kk = 0; kk < 32; kk++) {
            float4 av = *(const float4*)&As[kk][ty * 4];
            float4 wv = *(const float4*)&Ws[kk][tx * 4];
            float a[4] = {av.x, av.y, av.z, av.w};
            float w[4] = {wv.x, wv.y, wv.z, wv.w};
            #pragma unroll
            for (int mi = 0; mi < 4; mi++)
                #pragma unroll
                for (int ni = 0; ni < 4; ni++)
                    acc[mi][ni] += a[mi] * w[ni];
        }
        __syncthreads();
    }
    #pragma unroll
    for (int mi = 0; mi < 4; mi++) {
        int gm = ty * 4 + mi;
        float scv = alpha * rowscale[(long)b * 64 + gm];
        #pragma unroll
        for (int ni = 0; ni < 4; ni++) {
            float v = scv * acc[mi][ni];
            unsigned short hh, ll; bsplit(v, hh, ll);
            long off = ((long)b * DIM + n0 + tx * 4 + ni) * 128 + hoff + gm;
            ihiT[off] = hh; iloT[off] = ll;
        }
    }
}

// ============ gemm_head: M=64,N=K=512, epi: relu((acc + m*q)/num) ============
__global__ __launch_bounds__(256) void gemm_head(
    const float* __restrict__ A, long sA,
    const float* __restrict__ W,
    float* __restrict__ C, long sC,
    const int* __restrict__ mrow, const float* __restrict__ addvec,
    const float* __restrict__ rownum)
{
    int b = blockIdx.z;
    int n0 = blockIdx.x * 64;
    __shared__ float As[32][68], Ws[32][68];
    float acc[4][4] = {};
    int tx = threadIdx.x & 15, ty = threadIdx.x >> 4;
    int lm = threadIdx.x >> 2, lk = (threadIdx.x & 3) * 8;
    const float* Ab = A + (long)b * sA;
    for (int k0 = 0; k0 < DIM; k0 += 32) {
        const float4* pa = (const float4*)(Ab + (long)lm * DIM + k0 + lk);
        float4 va0 = pa[0], va1 = pa[1];
        const float4* pw = (const float4*)(W + (long)(n0 + lm) * DIM + k0 + lk);
        float4 vw0 = pw[0], vw1 = pw[1];
        As[lk + 0][lm] = va0.x; As[lk + 1][lm] = va0.y; As[lk + 2][lm] = va0.z; As[lk + 3][lm] = va0.w;
        As[lk + 4][lm] = va1.x; As[lk + 5][lm] = va1.y; As[lk + 6][lm] = va1.z; As[lk + 7][lm] = va1.w;
        Ws[lk + 0][lm] = vw0.x; Ws[lk + 1][lm] = vw0.y; Ws[lk + 2][lm] = vw0.z; Ws[lk + 3][lm] = vw0.w;
        Ws[lk + 4][lm] = vw1.x; Ws[lk + 5][lm] = vw1.y; Ws[lk + 6][lm] = vw1.z; Ws[lk + 7][lm] = vw1.w;
        __syncthreads();
        #pragma unroll
        for (int kk = 0; kk < 32; kk++) {
            float4 av = *(const float4*)&As[kk][ty * 4];
            float4 wv = *(const float4*)&Ws[kk][tx * 4];
            float a[4] = {av.x, av.y, av.z, av.w};
            float w[4] = {wv.x, wv.y, wv.z, wv.w};
            #pragma unroll
            for (int mi = 0; mi < 4; mi++)
                #pragma unroll
                for (int ni = 0; ni < 4; ni++)
                    acc[mi][ni] += a[mi] * w[ni];
        }
        __syncthreads();
    }
    #pragma unroll
    for (int mi = 0; mi < 4; mi++) {
        int gm = ty * 4 + mi;
        float mq = (mrow[(long)b * 64 + gm] != 0) ? 1.f : 0.f;
        float inv = 1.f / rownum[(long)b * 64 + gm];
        float4 o;
        float* vo = (float*)&o;
        #pragma unroll
        for (int ni = 0; ni < 4; ni++) {
            float tv = (acc[mi][ni] + mq * addvec[(long)b * DIM + n0 + tx * 4 + ni]) * inv;
            vo[ni] = fmaxf(tv, 0.f);
        }
        *(float4*)(C + (long)b * sC + (long)gm * DIM + n0 + tx * 4) = o;
    }
}

// ============ pre_r/pre_c via MFMA: [rel_rd ; rel_cd] (128x2048) @ dcsum (2048x512) ============
__global__ __launch_bounds__(256) void k_pre_rc_mfma(
    const int* __restrict__ rel_rd, const int* __restrict__ rel_cd,
    const unsigned short* __restrict__ thi, const unsigned short* __restrict__ tlo,
    const int* __restrict__ rm, const int* __restrict__ cm,
    float* __restrict__ pre_r, float* __restrict__ pre_c)
{
    int b = blockIdx.y, n0 = blockIdx.x * 64;
    __shared__ unsigned short Aexp[128 * 64];
    __shared__ unsigned short Bhi[64 * 64], Blo[64 * 64];
    int tid = threadIdx.x, lane = tid & 63, wid = tid >> 6;
    int wm = wid >> 1, wn = wid & 1;
    int arow = tid >> 1, aseg = tid & 1;
    const int* relrow = (arow < 64)
        ? rel_rd + ((long)b * 64 + arow) * ND
        : rel_cd + ((long)b * 64 + arow - 64) * ND;
    int bn = tid >> 2, bq = tid & 3;
    const unsigned short* bsrc_h = thi + ((long)b * DIM + n0 + bn) * ND;
    const unsigned short* bsrc_l = tlo + ((long)b * DIM + n0 + bn) * ND;

    f32x4 acc[4][2];
    #pragma unroll
    for (int i = 0; i < 4; i++)
        #pragma unroll
        for (int j = 0; j < 2; j++)
            acc[i][j] = (f32x4){0.f, 0.f, 0.f, 0.f};

    for (int k0 = 0; k0 < ND; k0 += 64) {
        {
            const int4* pa = (const int4*)(relrow + k0 + aseg * 32);
            #pragma unroll
            for (int p = 0; p < 4; p++) {
                int4 v0 = pa[2 * p], v1 = pa[2 * p + 1];
                uint4 qv;
                qv.x = (v0.x ? 0x3F80u : 0u) | (v0.y ? 0x3F800000u : 0u);
                qv.y = (v0.z ? 0x3F80u : 0u) | (v0.w ? 0x3F800000u : 0u);
                qv.z = (v1.x ? 0x3F80u : 0u) | (v1.y ? 0x3F800000u : 0u);
                qv.w = (v1.z ? 0x3F80u : 0u) | (v1.w ? 0x3F800000u : 0u);
                int c = (aseg * 4 + p) ^ (arow & 7);
                *(uint4*)((char*)Aexp + arow * 128 + c * 16) = qv;
            }
        }
        {
            const uint4* ph = (const uint4*)(bsrc_h + k0 + bq * 16);
            const uint4* pl = (const uint4*)(bsrc_l + k0 + bq * 16);
            #pragma unroll
            for (int s = 0; s < 2; s++) {
                int c = (bq * 2 + s) ^ (bn & 7);
                *(uint4*)((char*)Bhi + bn * 128 + c * 16) = ph[s];
                *(uint4*)((char*)Blo + bn * 128 + c * 16) = pl[s];
            }
        }
        __syncthreads();
        #pragma unroll
        for (int ks = 0; ks < 2; ks++) {
            bf16x8 af[4], bh[2], bl[2];
            #pragma unroll
            for (int i = 0; i < 4; i++) {
                int rr = wm * 64 + i * 16 + (lane & 15);
                int cc = (ks * 4 + (lane >> 4)) ^ (rr & 7);
                af[i] = *(bf16x8*)((char*)Aexp + rr * 128 + cc * 16);
            }
            #pragma unroll
            for (int i = 0; i < 2; i++) {
                int nn = wn * 32 + i * 16 + (lane & 15);
                int c2 = (ks * 4 + (lane >> 4)) ^ (nn & 7);
                bh[i] = *(bf16x8*)((char*)Bhi + nn * 128 + c2 * 16);
                bl[i] = *(bf16x8*)((char*)Blo + nn * 128 + c2 * 16);
            }
            #pragma unroll
            for (int mi = 0; mi < 4; mi++)
                #pragma unroll
                for (int ni = 0; ni < 2; ni++) {
                    acc[mi][ni] = __builtin_amdgcn_mfma_f32_16x16x32_bf16(af[mi], bh[ni], acc[mi][ni], 0, 0, 0);
                    acc[mi][ni] = __builtin_amdgcn_mfma_f32_16x16x32_bf16(af[mi], bl[ni], acc[mi][ni], 0, 0, 0);
                }
        }
        __syncthreads();
    }
    const int* msk = wm ? cm : rm;
    float* outp = wm ? pre_c : pre_r;
    #pragma unroll
    for (int mi = 0; mi < 4; mi++) {
        int grow = mi * 16 + (lane >> 4) * 4;
        #pragma unroll
        for (int ni = 0; ni < 2; ni++) {
            int gcol = n0 + wn * 32 + ni * 16 + (lane & 15);
            #pragma unroll
            for (int r = 0; r < 4; r++) {
                int rrow = grow + r;
                float scv = (msk[b * 64 + rrow] != 0) ? 1.f : 0.f;
                outp[((long)b * 64 + rrow) * DIM + gcol] = scv * acc[mi][ni][r];
            }
        }
    }
}

// ============ projT = Wsr-split @ dcs-split^T via MFMA; LDS-transposed coalesced epilogue ============
__global__ __launch_bounds__(256) void k_proj_mfma(
    const unsigned short* __restrict__ whi, const unsigned short* __restrict__ wlo,
    const unsigned short* __restrict__ dhi, const unsigned short* __restrict__ dlo,
    unsigned short* __restrict__ phi, unsigned short* __restrict__ plo)
{
    int flat = blockIdx.x;                   // 1024 blocks
    int tile = (flat & 7) * 128 + (flat >> 3);
    int b = tile >> 6;
    int rem = tile & 63;
    int m0 = (rem >> 4) * 128;
    int n0 = (rem & 15) * 128;

    __shared__ unsigned short SM[4 * 128 * 64];   // 64 KB, partitioned
    unsigned short* Ahi = SM;
    unsigned short* Alo = SM + 128 * 64;
    unsigned short* Bhi = SM + 2 * 128 * 64;
    unsigned short* Blo = SM + 3 * 128 * 64;

    int tid = threadIdx.x;
    int lane = tid & 63, wid = tid >> 6;
    int wm = wid >> 1, wn = wid & 1;
    int srow = tid >> 1, sseg = tid & 1;

    f32x4 acc[4][4];
    #pragma unroll
    for (int i = 0; i < 4; i++)
        #pragma unroll
        for (int j = 0; j < 4; j++)
            acc[i][j] = (f32x4){0.f, 0.f, 0.f, 0.f};

    for (int k0 = 0; k0 < DIM; k0 += 64) {
        {
            const uint4* ph = (const uint4*)(whi + (long)(m0 + srow) * DIM + k0 + sseg * 32);
            const uint4* pl = (const uint4*)(wlo + (long)(m0 + srow) * DIM + k0 + sseg * 32);
            #pragma unroll
            for (int s = 0; s < 4; s++) {
                int c = (sseg * 4 + s) ^ (srow & 7);
                *(uint4*)((char*)Ahi + srow * 128 + c * 16) = ph[s];
                *(uint4*)((char*)Alo + srow * 128 + c * 16) = pl[s];
            }
        }
        {
            const uint4* ph = (const uint4*)(dhi + ((long)b * ND + n0 + srow) * DIM + k0 + sseg * 32);
            const uint4* pl = (const uint4*)(dlo + ((long)b * ND + n0 + srow) * DIM + k0 + sseg * 32);
            #pragma unroll
            for (int s = 0; s < 4; s++) {
                int c = (sseg * 4 + s) ^ (srow & 7);
                *(uint4*)((char*)Bhi + srow * 128 + c * 16) = ph[s];
                *(uint4*)((char*)Blo + srow * 128 + c * 16) = pl[s];
            }
        }
        __syncthreads();
        #pragma unroll
        for (int ks = 0; ks < 2; ks++) {
            bf16x8 ah[4], al[4], bh[4], bl[4];
            #pragma unroll
            for (int i = 0; i < 4; i++) {
                int rr = wm * 64 + i * 16 + (lane & 15);
                int cc = (ks * 4 + (lane >> 4)) ^ (rr & 7);
                ah[i] = *(bf16x8*)((char*)Ahi + rr * 128 + cc * 16);
                al[i] = *(bf16x8*)((char*)Alo + rr * 128 + cc * 16);
                int nn = wn * 64 + i * 16 + (lane & 15);
                int c2 = (ks * 4 + (lane >> 4)) ^ (nn & 7);
                bh[i] = *(bf16x8*)((char*)Bhi + nn * 128 + c2 * 16);
                bl[i] = *(bf16x8*)((char*)Blo + nn * 128 + c2 * 16);
            }
            #pragma unroll
            for (int mi = 0; mi < 4; mi++)
                #pragma unroll
                for (int ni = 0; ni < 4; ni++) {
                    acc[mi][ni] = __builtin_amdgcn_mfma_f32_16x16x32_bf16(ah[mi], bh[ni], acc[mi][ni], 0, 0, 0);
                    acc[mi][ni] = __builtin_amdgcn_mfma_f32_16x16x32_bf16(ah[mi], bl[ni], acc[mi][ni], 0, 0, 0);
                    acc[mi][ni] = __builtin_amdgcn_mfma_f32_16x16x32_bf16(al[mi], bh[ni], acc[mi][ni], 0, 0, 0);
                }
        }
        __syncthreads();
    }
    // ---- epilogue: split acc -> LDS transpose -> coalesced us8 stores ----
    unsigned short* Ph = SM;                 // [128][128] hi plane (32 KB)
    unsigned short* Pl = SM + 128 * 128;     // [128][128] lo plane (32 KB)
    #pragma unroll
    for (int mi = 0; mi < 4; mi++) {
        int lrow = wm * 64 + mi * 16 + (lane >> 4) * 4;
        #pragma unroll
        for (int ni = 0; ni < 4; ni++) {
            int lcol = wn * 64 + ni * 16 + (lane & 15);
            #pragma unroll
            for (int r = 0; r < 4; r++) {
                unsigned short hh, ll; bsplit(acc[mi][ni][r], hh, ll);
                int row = lrow + r;
                int cs = lcol ^ ((row & 3) << 4);
                Ph[row * 128 + cs] = hh;
                Pl[row * 128 + cs] = ll;
            }
        }
    }
    __syncthreads();
    {
        int row = tid >> 1, half = tid & 1;
        long gbase = ((long)b * DIM + m0 + row) * ND + n0 + half * 64;
        int xs = (row & 3) << 4;
        #pragma unroll
        for (int s = 0; s < 8; s++) {
            int col = (half * 64 + s * 8) ^ xs;
            *(us8*)(phi + gbase + s * 8) = *(const us8*)(Ph + row * 128 + col);
            *(us8*)(plo + gbase + s * 8) = *(const us8*)(Pl + row * 128 + col);
        }
    }
}

// ============ final dc: relu((bits @ (phi+plo) + rel^T @ info) / dc_num) ============
__global__ __launch_bounds__(256) void k_agg_final(
    const unsigned* __restrict__ bits,
    const unsigned short* __restrict__ phi, const unsigned short* __restrict__ plo,
    const unsigned short* __restrict__ ihiT, const unsigned short* __restrict__ iloT,
    const int* __restrict__ rel_rd, const int* __restrict__ rel_cd,
    const int* __restrict__ dmask, const float* __restrict__ rownum,
    float* __restrict__ out)
{
    int flat = blockIdx.x;
    int tile = (flat & 7) * 128 + (flat >> 3);
    int b = tile >> 6;
    int m0 = ((tile >> 2) & 15) * 128;
    int n0 = (tile & 3) * 128;

    __shared__ unsigned short Aexp[128 * 64];
    __shared__ unsigned short Bhi[128 * 64];
    __shared__ unsigned short Blo[128 * 64];
    __shared__ unsigned short dmu[128];
    __shared__ unsigned LDSw[256];

    int tid = threadIdx.x;
    int lane = tid & 63, wid = tid >> 6;
    int wm = wid >> 1, wn = wid & 1;

    if (tid < 128) dmu[tid] = (dmask[(long)b * ND + m0 + tid] != 0) ? (unsigned short)0x3F80 : (unsigned short)0;

    int arow = tid >> 1, awsel = tid & 1;
    const unsigned* abit_base = bits + ((long)b * ND + m0 + arow) * 64 + awsel;
    char* adst = (char*)Aexp + arow * 128;

    f32x4 acc[4][4];
    #pragma unroll
    for (int i = 0; i < 4; i++)
        #pragma unroll
        for (int j = 0; j < 4; j++)
            acc[i][j] = (f32x4){0.f, 0.f, 0.f, 0.f};

    // ---- main loop: 32 K-tiles over graph bits x proj planes ----
    for (int k0 = 0; k0 < ND; k0 += 64) {
        #pragma unroll
        for (int u = 0; u < 8; u++) {
            int lin = (u & 3) * 256 + tid;
            int n = lin >> 3, c = lin & 7;
            const unsigned short* src = (u < 4 ? phi : plo)
                + ((long)b * DIM + n0 + n) * ND + k0 + c * 8;
            uint4 v = *(const uint4*)src;
            char* dst = (char*)(u < 4 ? Bhi : Blo) + n * 128 + ((c ^ (n & 7)) * 16);
            *(uint4*)dst = v;
        }
        {
            unsigned w = abit_base[k0 >> 5];
            #pragma unroll
            for (int c = 0; c < 4; c++) {
                uint4 qv;
                qv.x = (((w >> (c * 8 + 0)) & 1u) ? 0x3F80u : 0u) | (((w >> (c * 8 + 1)) & 1u) ? 0x3F800000u : 0u);
                qv.y = (((w >> (c * 8 + 2)) & 1u) ? 0x3F80u : 0u) | (((w >> (c * 8 + 3)) & 1u) ? 0x3F800000u : 0u);
                qv.z = (((w >> (c * 8 + 4)) & 1u) ? 0x3F80u : 0u) | (((w >> (c * 8 + 5)) & 1u) ? 0x3F800000u : 0u);
                qv.w = (((w >> (c * 8 + 6)) & 1u) ? 0x3F80u : 0u) | (((w >> (c * 8 + 7)) & 1u) ? 0x3F800000u : 0u);
                int chunk = (awsel * 4 + c) ^ (arow & 7);
                *(uint4*)(adst + chunk * 16) = qv;
            }
        }
        __syncthreads();
        mfma_phase2(Aexp, Bhi, Blo, wm, wn, lane, acc);
        __syncthreads();
    }
    // ---- fused header-info tiles: 2 x K=64 over rel^T x infoT planes ----
    #pragma unroll
    for (int kt = 0; kt < 2; kt++) {
        #pragma unroll
        for (int u = 0; u < 8; u++) {
            int lin = (u & 3) * 256 + tid;
            int n = lin >> 3, c = lin & 7;
            uint4 v = *(const uint4*)((u < 4 ? ihiT : iloT)
                + ((long)b * DIM + n0 + n) * 128 + kt * 64 + c * 8);
            char* dst = (char*)(u < 4 ? Bhi : Blo) + n * 128 + ((c ^ (n & 7)) * 16);
            *(uint4*)dst = v;
        }
        const int* relrow = (kt ? rel_cd : rel_rd) + ((long)b * 64 + lane) * ND + m0 + wid * 32;
        #pragma unroll
        for (int c4 = 0; c4 < 32; c4 += 4) {
            int4 v = *(const int4*)(relrow + c4);
            unsigned long long mm;
            mm = __ballot(v.x != 0);
            if ((lane >> 1) == c4 + 0) LDSw[(wid * 32 + c4 + 0) * 2 + (lane & 1)] = (unsigned)(mm >> ((lane & 1) * 32));
            mm = __ballot(v.y != 0);
            if ((lane >> 1) == c4 + 1) LDSw[(wid * 32 + c4 + 1) * 2 + (lane & 1)] = (unsigned)(mm >> ((lane & 1) * 32));
            mm = __ballot(v.z != 0);
            if ((lane >> 1) == c4 + 2) LDSw[(wid * 32 + c4 + 2) * 2 + (lane & 1)] = (unsigned)(mm >> ((lane & 1) * 32));
            mm = __ballot(v.w != 0);
            if ((lane >> 1) == c4 + 3) LDSw[(wid * 32 + c4 + 3) * 2 + (lane & 1)] = (unsigned)(mm >> ((lane & 1) * 32));
        }
        __syncthreads();
        {
            unsigned w = LDSw[arow * 2 + awsel];
            unsigned dv = (unsigned)dmu[arow];
            unsigned dvh = dv << 16;
            #pragma unroll
            for (int c = 0; c < 4; c++) {
                uint4 qv;
                qv.x = (((w >> (c * 8 + 0)) & 1u) ? dv : 0u) | (((w >> (c * 8 + 1)) & 1u) ? dvh : 0u);
                qv.y = (((w >> (c * 8 + 2)) & 1u) ? dv : 0u) | (((w >> (c * 8 + 3)) & 1u) ? dvh : 0u);
                qv.z = (((w >> (c * 8 + 4)) & 1u) ? dv : 0u) | (((w >> (c * 8 + 5)) & 1u) ? dvh : 0u);
                qv.w = (((w >> (c * 8 + 6)) & 1u) ? dv : 0u) | (((w >> (c * 8 + 7)) & 1u) ? dvh : 0u);
                int chunk = (awsel * 4 + c) ^ (arow & 7);
                *(uint4*)(adst + chunk * 16) = qv;
            }
        }
        __syncthreads();
        mfma_phase2(Aexp, Bhi, Blo, wm, wn, lane, acc);
        __syncthreads();
    }
    // ---- epilogue ----
    #pragma unroll
    for (int mi = 0; mi < 4; mi++) {
        int grow = m0 + wm * 64 + mi * 16 + (lane >> 4) * 4;
        float inv[4];
        #pragma unroll
        for (int r = 0; r < 4; r++) inv[r] = 1.f / rownum[(long)b * ND + grow + r];
        #pragma unroll
        for (int ni = 0; ni < 4; ni++) {
            int gcol = n0 + wn * 64 + ni * 16 + (lane & 15);
            #pragma unroll
            for (int r = 0; r < 4; r++) {
                long off = ((long)b * ND + grow + r) * DIM + gcol;
                out[off] = fmaxf(acc[mi][ni][r] * inv[r], 0.f);
            }
        }
    }
}

// ==================================================================================
extern "C" void kernel_launch(void* const* d_in, const int* in_sizes, int n_in,
                              void* d_out, int out_size, void* d_ws, size_t ws_size,
                              hipStream_t stream)
{
    const float* q       = (const float*)d_in[0];
    const float* rh0     = (const float*)d_in[1];
    const float* ch0     = (const float*)d_in[2];
    const float* dc0     = (const float*)d_in[3];
    const int*   rm      = (const int*)d_in[4];
    const int*   cm      = (const int*)d_in[5];
    const int*   dmask   = (const int*)d_in[6];
    const int*   same_row= (const int*)d_in[7];
    const int*   same_col= (const int*)d_in[8];
    const int*   rel_rd  = (const int*)d_in[9];
    const int*   rel_cd  = (const int*)d_in[10];
    const float* wnode   = (const float*)d_in[11];
    const float* w_rdc   = (const float*)d_in[12];
    const float* w_cdc   = (const float*)d_in[13];
    const float* w_dcr   = (const float*)d_in[14];
    const float* w_dcc   = (const float*)d_in[15];
    const float* w_sr    = (const float*)d_in[16];
    const float* w_rq    = (const float*)d_in[18];
    const float* w_cq    = (const float*)d_in[19];

    float* out = (float*)d_out;
    float* rh = out;                           // [16,64,512]
    float* ch = out + (long)NB * NR * DIM;     // [16,64,512]
    float* dc = out + (long)NB * NR * DIM * 2; // [16,2048,512]

    if (ws_size < (size_t)WS_FLOATS * 4) return;

    float* ws      = (float*)d_ws;
    float* rh_num  = ws + OFF_RHNUM;
    float* ch_num  = ws + OFF_CHNUM;
    float* dc_num  = ws + OFF_DCNUM;
    float* rh_w    = ws + OFF_RHW;
    float* ch_w    = ws + OFF_CHW;
    float* qrow    = ws + OFF_QROW;
    float* qcol    = ws + OFF_QCOL;
    float* pre_r   = ws + OFF_PRER;
    float* pre_c   = ws + OFF_PREC;
    unsigned short* ihiT = (unsigned short*)(ws + OFF_INFORC);  // [16][512][128]
    unsigned short* iloT = ihiT + (size_t)NB * DIM * 128;
    unsigned* bits = (unsigned*)(ws + OFF_BITS);
    unsigned short* dhi = (unsigned short*)(ws + OFF_DCS);
    unsigned short* dlo = dhi + (size_t)NB * ND * DIM;
    unsigned short* thi = (unsigned short*)(ws + OFF_PROJ);  // transposed dcs planes
    unsigned short* tlo = thi + (size_t)NB * DIM * ND;
    unsigned short* phi = (unsigned short*)(ws + OFF_PROJ);  // proj planes overwrite thi/tlo (dead)
    unsigned short* plo = phi + (size_t)NB * DIM * ND;
    // whi/wlo in out-dc slice (dead between k_split-read and k_agg_final-write)
    unsigned short* whi = (unsigned short*)dc;
    unsigned short* wlo = whi + (size_t)DIM * DIM;

    hipMemcpyAsync(rh, rh0, sizeof(float) * (size_t)NB * NR * DIM, hipMemcpyDeviceToDevice, stream);
    hipMemcpyAsync(ch, ch0, sizeof(float) * (size_t)NB * NCOL * DIM, hipMemcpyDeviceToDevice, stream);

    k_bits<<<NB * ND / 2, 256, 0, stream>>>(same_row, same_col, dmask, bits, dc_num);
    k_rcnum<<<512, 256, 0, stream>>>(rel_rd, rel_cd, rm, cm, dmask, rh_num, ch_num);
    k_dcnum_final<<<dim3(ND / 256, NB), 256, 0, stream>>>(rel_rd, rel_cd, rm, cm, dmask, dc_num);
    k_q<<<dim3(128, 2, NB), 256, 0, stream>>>(q, w_rq, w_cq, qrow, qcol);

    for (int it = 0; it < 2; it++) {
        k_gate_rc<<<512, 256, 0, stream>>>(rh, ch, rm, cm, wnode, rh_w, ch_w);
        k_split<<<dim3(128, NB), 256, 0, stream>>>(it == 0 ? dc0 : dc, wnode, dmask, dhi, dlo, thi, tlo);
        k_wsplit<<<128, 256, 0, stream>>>(w_sr, whi, wlo);
        gemm_info<<<dim3(8, 1, NB), 256, 0, stream>>>(rh, (long)NR * DIM, w_dcr,
            ihiT, iloT, 0, rh_w, 1.0f);
        gemm_info<<<dim3(8, 1, NB), 256, 0, stream>>>(ch, (long)NCOL * DIM, w_dcc,
            ihiT, iloT, 64, ch_w, 2.0f);
        k_pre_rc_mfma<<<dim3(8, NB), 256, 0, stream>>>(rel_rd, rel_cd, thi, tlo, rm, cm, pre_r, pre_c);
        k_proj_mfma<<<1024, 256, 0, stream>>>(whi, wlo, dhi, dlo, phi, plo);
        gemm_head<<<dim3(8, 1, NB), 256, 0, stream>>>(pre_r, (long)NR * DIM, w_rdc,
            rh, (long)NR * DIM, rm, qrow, rh_num);
        gemm_head<<<dim3(8, 1, NB), 256, 0, stream>>>(pre_c, (long)NCOL * DIM, w_cdc,
            ch, (long)NCOL * DIM, cm, qcol, ch_num);
        k_agg_final<<<1024, 256, 0, stream>>>(bits, phi, plo, ihiT, iloT,
            rel_rd, rel_cd, dmask, dc_num, dc);
    }
}

// Round 9
// 1074.191 us; speedup vs baseline: 1.0658x; 1.0658x over previous
//
#include <hip/hip_runtime.h>
#include <math.h>

#define NB 16
#define NR 64
#define NCOL 64
#define ND 2048
#define DIM 512

typedef __attribute__((ext_vector_type(4))) float f32x4;
typedef __attribute__((ext_vector_type(8))) short bf16x8;
typedef __attribute__((ext_vector_type(8))) unsigned short us8;

// async global->LDS, 16B per lane, linear LDS dest (wave-uniform base + lane*16)
#define GLD(src, dst) __builtin_amdgcn_global_load_lds( \
    (const __attribute__((address_space(1))) void*)(src), \
    (__attribute__((address_space(3))) void*)(dst), 16, 0, 0)

// ---------------- workspace layout (float offsets) ----------------
#define OFF_RHNUM  0L
#define OFF_CHNUM  1024L
#define OFF_DCNUM  2048L
#define OFF_RHW    34816L
#define OFF_CHW    35840L
#define OFF_QROW   36864L
#define OFF_QCOL   45056L
#define OFF_PRER   53248L
#define OFF_PREC   577536L
#define OFF_INFORC 1101824L   // ihiT/iloT bf16 info planes [b][512][128] (4 MB)
#define OFF_BITS   2150400L
#define OFF_DCS    4247552L   // dhi/dlo row-major planes
#define OFF_PROJ   21024768L  // thi/tlo transposed dcs planes, then phi/plo proj planes
#define WS_FLOATS  37801984L  // 151.2 MB
// whi/wlo live in the out-dc slice (dead mid-iteration)

// RNE fp32 -> bf16 split: v ~= hi + lo, both bf16
__device__ inline void bsplit(float v, unsigned short& h, unsigned short& l) {
    unsigned uv = __float_as_uint(v);
    unsigned hb = (uv + 0x7FFFu + ((uv >> 16) & 1u)) >> 16;
    h = (unsigned short)hb;
    float lo = v - __uint_as_float(hb << 16);
    unsigned lv = __float_as_uint(lo);
    l = (unsigned short)((lv + 0x7FFFu + ((lv >> 16) & 1u)) >> 16);
}

// spread 8 bits to every 4th position of a 32-bit word
__device__ inline unsigned spread4(unsigned x) {
    x = (x | (x << 12)) & 0x000F000Fu;
    x = (x | (x << 6))  & 0x03030303u;
    x = (x | (x << 3))  & 0x11111111u;
    return x;
}

// shared MFMA phase: 2 ks x (4x4) x 2 products (A exact, B hi+lo)
__device__ inline void mfma_phase2(const unsigned short* Aexp, const unsigned short* Bhi,
                                   const unsigned short* Blo, int wm, int wn, int lane,
                                   f32x4 acc[4][4])
{
    #pragma unroll
    for (int ks = 0; ks < 2; ks++) {
        bf16x8 af[4], bh[4], bl[4];
        #pragma unroll
        for (int i = 0; i < 4; i++) {
            int rr = wm * 64 + i * 16 + (lane & 15);
            int cc = (ks * 4 + (lane >> 4)) ^ (rr & 7);
            af[i] = *(const bf16x8*)((const char*)Aexp + rr * 128 + cc * 16);
            int nn = wn * 64 + i * 16 + (lane & 15);
            int c2 = (ks * 4 + (lane >> 4)) ^ (nn & 7);
            bh[i] = *(const bf16x8*)((const char*)Bhi + nn * 128 + c2 * 16);
            bl[i] = *(const bf16x8*)((const char*)Blo + nn * 128 + c2 * 16);
        }
        #pragma unroll
        for (int mi = 0; mi < 4; mi++)
            #pragma unroll
            for (int ni = 0; ni < 4; ni++) {
                acc[mi][ni] = __builtin_amdgcn_mfma_f32_16x16x32_bf16(af[mi], bh[ni], acc[mi][ni], 0, 0, 0);
                acc[mi][ni] = __builtin_amdgcn_mfma_f32_16x16x32_bf16(af[mi], bl[ni], acc[mi][ni], 0, 0, 0);
            }
    }
}

// ============ gate for rh/ch rows ============
__global__ __launch_bounds__(256) void k_gate_rc(
    const float* __restrict__ rh, const float* __restrict__ ch,
    const int* __restrict__ rm, const int* __restrict__ cm,
    const float* __restrict__ wnode,
    float* __restrict__ rh_w, float* __restrict__ ch_w)
{
    int wave = threadIdx.x >> 6, lane = threadIdx.x & 63;
    int idx = blockIdx.x * 4 + wave;   // < 2048
    const float* xrow; float* outw; int mval;
    if (idx < NB * NR) {
        int b = idx >> 6, r = idx & 63;
        xrow = rh + ((long)b * NR + r) * DIM; mval = rm[b * NR + r]; outw = rh_w + b * NR + r;
    } else {
        int tt = idx - NB * NR; int b = tt >> 6, c = tt & 63;
        xrow = ch + ((long)b * NCOL + c) * DIM; mval = cm[b * NCOL + c]; outw = ch_w + b * NCOL + c;
    }
    const float4* px = (const float4*)xrow;
    const float4* pw = (const float4*)wnode;
    float4 xa = px[lane * 2], xb = px[lane * 2 + 1];
    float4 wa = pw[lane * 2], wb = pw[lane * 2 + 1];
    float s = xa.x * wa.x + xa.y * wa.y + xa.z * wa.z + xa.w * wa.w
            + xb.x * wb.x + xb.y * wb.y + xb.z * wb.z + xb.w * wb.w;
    #pragma unroll
    for (int o = 32; o > 0; o >>= 1) s += __shfl_xor(s, o, 64);
    if (lane == 0) {
        float g = 1.f / (1.f + expf(-s));
        *outw = mval ? g : 0.f;
    }
}

// ============ gate+split dc -> dhi/dlo [b][2048][512] AND thi/tlo [b][512][2048] ============
__global__ __launch_bounds__(256) void k_split(
    const float* __restrict__ src, const float* __restrict__ wnode, const int* __restrict__ dmask,
    unsigned short* __restrict__ dhi, unsigned short* __restrict__ dlo,
    unsigned short* __restrict__ thi, unsigned short* __restrict__ tlo)
{
    int b = blockIdx.y, j0 = blockIdx.x * 16;
    __shared__ float X[16 * 512];
    __shared__ float scs[16];
    int t = threadIdx.x;
    int r = t >> 4, u = t & 15;
    const float* row = src + ((long)b * ND + j0 + r) * DIM;
    float part = 0.f;
    #pragma unroll
    for (int i = 0; i < 8; i++) {
        int col = i * 64 + u * 4;
        float4 v = *(const float4*)(row + col);
        float4 w = *(const float4*)(wnode + col);
        part += v.x * w.x + v.y * w.y + v.z * w.z + v.w * w.w;
        *(float4*)&X[r * 512 + (col ^ ((r & 7) * 4))] = v;
    }
    part += __shfl_xor(part, 1, 64);
    part += __shfl_xor(part, 2, 64);
    part += __shfl_xor(part, 4, 64);
    part += __shfl_xor(part, 8, 64);
    if (u == 0) {
        float g = 1.f / (1.f + expf(-part));
        scs[r] = (dmask[(long)b * ND + j0 + r] != 0) ? g : 0.f;
    }
    __syncthreads();
    // row-major planes
    {
        float s = scs[r];
        long ob = ((long)b * ND + j0 + r) * DIM + u * 32;
        #pragma unroll
        for (int g = 0; g < 4; g++) {
            us8 ph, pl;
            #pragma unroll
            for (int e = 0; e < 8; e++) {
                int cc = u * 32 + g * 8 + e;
                float v = X[r * 512 + (cc ^ ((r & 7) * 4))] * s;
                unsigned short hh, ll; bsplit(v, hh, ll);
                ph[e] = hh; pl[e] = ll;
            }
            *(us8*)(dhi + ob + g * 8) = ph;
            *(us8*)(dlo + ob + g * 8) = pl;
        }
    }
    // transposed planes
    #pragma unroll
    for (int h = 0; h < 2; h++) {
        int n = t + h * 256;
        us8 ph0, ph1, pl0, pl1;
        #pragma unroll
        for (int rr = 0; rr < 16; rr++) {
            float v = X[rr * 512 + (n ^ ((rr & 7) * 4))] * scs[rr];
            unsigned short hh, ll; bsplit(v, hh, ll);
            if (rr < 8) { ph0[rr] = hh; pl0[rr] = ll; }
            else        { ph1[rr - 8] = hh; pl1[rr - 8] = ll; }
        }
        long ob = ((long)b * DIM + n) * ND + j0;
        *(us8*)(thi + ob) = ph0; *(us8*)(thi + ob + 8) = ph1;
        *(us8*)(tlo + ob) = pl0; *(us8*)(tlo + ob + 8) = pl1;
    }
}

// ============ split w_sr -> whi/wlo bf16 [512][512] ============
__global__ __launch_bounds__(256) void k_wsplit(
    const float* __restrict__ w, unsigned short* __restrict__ whi, unsigned short* __restrict__ wlo)
{
    long i = ((long)blockIdx.x * 256 + threadIdx.x) * 8;
    float4 a = *(const float4*)(w + i), b4 = *(const float4*)(w + i + 4);
    float v[8] = {a.x, a.y, a.z, a.w, b4.x, b4.y, b4.z, b4.w};
    us8 ph, pl;
    #pragma unroll
    for (int t = 0; t < 8; t++) {
        unsigned short hh, ll; bsplit(v[t], hh, ll);
        ph[t] = hh; pl[t] = ll;
    }
    *(us8*)(whi + i) = ph;
    *(us8*)(wlo + i) = pl;
}

// ============ q projections (once) ============
__global__ __launch_bounds__(256) void k_q(
    const float* __restrict__ q, const float* __restrict__ wrq, const float* __restrict__ wcq,
    float* __restrict__ qrow, float* __restrict__ qcol)
{
    int b = blockIdx.z;
    const float* W = blockIdx.y ? wcq : wrq;
    float* out = blockIdx.y ? qcol : qrow;
    int wave = threadIdx.x >> 6, lane = threadIdx.x & 63;
    int n = blockIdx.x * 4 + wave;
    const float4* qp = (const float4*)(q + (long)b * DIM);
    const float4* wp = (const float4*)(W + (long)n * DIM);
    float4 a0 = qp[lane * 2], a1 = qp[lane * 2 + 1];
    float4 w0 = wp[lane * 2], w1 = wp[lane * 2 + 1];
    float s = a0.x * w0.x + a0.y * w0.y + a0.z * w0.z + a0.w * w0.w
            + a1.x * w1.x + a1.y * w1.y + a1.z * w1.z + a1.w * w1.w;
    #pragma unroll
    for (int o = 32; o > 0; o >>= 1) s += __shfl_xor(s, o, 64);
    if (lane == 0) out[(long)b * DIM + n] = s;
}

// ============ pack same_row bits + partial dc_num: 2 rows/block, deep loads ============
__global__ __launch_bounds__(256) void k_bits(
    const int* __restrict__ sr, const int* __restrict__ sc, const int* __restrict__ dmask,
    unsigned* __restrict__ bits, float* __restrict__ dcnum)
{
    long bi0 = (long)blockIdx.x * 2;         // rows bi0, bi0+1 (same batch: ND even)
    int b = (int)(bi0 >> 11);
    int wave = threadIdx.x >> 6, lane = threadIdx.x & 63;
    const int4* dm4 = (const int4*)(dmask + (long)b * ND);
    int4 vs[2][2], vc[2][2], vd[2];
    #pragma unroll
    for (int h = 0; h < 2; h++) {
        int vidx = wave * 128 + h * 64 + lane;
        vd[h] = dm4[vidx];
        #pragma unroll
        for (int r = 0; r < 2; r++) {
            vs[r][h] = ((const int4*)(sr + (bi0 + r) * ND))[vidx];
            vc[r][h] = ((const int4*)(sc + (bi0 + r) * ND))[vidx];
        }
    }
    int dmi0 = dmask[bi0], dmi1 = dmask[bi0 + 1];
    __shared__ int red[2][4];
    #pragma unroll
    for (int r = 0; r < 2; r++) {
        int dmi = r ? dmi1 : dmi0;
        unsigned* brow = bits + (bi0 + r) * 64;
        int cnt = 0;
        #pragma unroll
        for (int h = 0; h < 2; h++) {
            int4 s4 = vs[r][h], c4 = vc[r][h], d4 = vd[h];
            bool d0 = dmi && d4.x, d1 = dmi && d4.y, d2 = dmi && d4.z, d3 = dmi && d4.w;
            unsigned long long m0 = __ballot(d0 && s4.x);
            unsigned long long m1 = __ballot(d1 && s4.y);
            unsigned long long m2 = __ballot(d2 && s4.z);
            unsigned long long m3 = __ballot(d3 && s4.w);
            unsigned long long n0 = __ballot(d0 && c4.x);
            unsigned long long n1 = __ballot(d1 && c4.y);
            unsigned long long n2 = __ballot(d2 && c4.z);
            unsigned long long n3 = __ballot(d3 && c4.w);
            cnt += __popcll(m0) + __popcll(m1) + __popcll(m2) + __popcll(m3)
                 + __popcll(n0) + __popcll(n1) + __popcll(n2) + __popcll(n3);
            if (lane < 8) {
                unsigned w = spread4((unsigned)(m0 >> (8 * lane)) & 0xFFu)
                           | (spread4((unsigned)(m1 >> (8 * lane)) & 0xFFu) << 1)
                           | (spread4((unsigned)(m2 >> (8 * lane)) & 0xFFu) << 2)
                           | (spread4((unsigned)(m3 >> (8 * lane)) & 0xFFu) << 3);
                brow[wave * 16 + h * 8 + lane] = w;
            }
        }
        if (lane == 0) red[r][wave] = cnt;
    }
    __syncthreads();
    if (threadIdx.x < 2) {
        int s = red[threadIdx.x][0] + red[threadIdx.x][1] + red[threadIdx.x][2] + red[threadIdx.x][3];
        dcnum[bi0 + threadIdx.x] = (float)s;
    }
}

// ============ rh_num / ch_num ============
__global__ __launch_bounds__(256) void k_rcnum(
    const int* __restrict__ rel_rd, const int* __restrict__ rel_cd,
    const int* __restrict__ rm, const int* __restrict__ cm, const int* __restrict__ dmask,
    float* __restrict__ rh_num, float* __restrict__ ch_num)
{
    int wave = threadIdx.x >> 6, lane = threadIdx.x & 63;
    long idx = (long)blockIdx.x * 4 + wave;  // < 2048
    const int* row; int mval; float* out; const int* dmb;
    if (idx < NB * NR) {
        int b = (int)(idx >> 6), r = (int)(idx & 63);
        row = rel_rd + ((long)b * NR + r) * ND; mval = rm[b * NR + r];
        out = rh_num + b * NR + r; dmb = dmask + (long)b * ND;
    } else {
        long tt = idx - NB * NR; int b = (int)(tt >> 6), c = (int)(tt & 63);
        row = rel_cd + ((long)b * NCOL + c) * ND; mval = cm[b * NCOL + c];
        out = ch_num + b * NCOL + c; dmb = dmask + (long)b * ND;
    }
    int cnt = 0;
    for (int rr = 0; rr < 32; rr++) {
        int j = rr * 64 + lane;
        cnt += (row[j] != 0 && dmb[j] != 0) ? 1 : 0;
    }
    #pragma unroll
    for (int o = 32; o > 0; o >>= 1) cnt += __shfl_xor(cnt, o, 64);
    if (lane == 0) {
        float s = mval ? (float)cnt : 0.f;
        *out = (s >= 1.f) ? (s + 1.f) : 1.f;
    }
}

// ============ finalize dc_num ============
__global__ __launch_bounds__(256) void k_dcnum_final(
    const int* __restrict__ rel_rd, const int* __restrict__ rel_cd,
    const int* __restrict__ rm, const int* __restrict__ cm, const int* __restrict__ dmask,
    float* __restrict__ dcnum)
{
    int b = blockIdx.y;
    int j = blockIdx.x * 256 + threadIdx.x;
    const int* rd = rel_rd + (long)b * NR * ND;
    const int* cd = rel_cd + (long)b * NCOL * ND;
    const int* rmb = rm + b * NR;
    const int* cmb = cm + b * NCOL;
    int cnt = 0;
    for (int r = 0; r < NR; r++)  cnt += (rd[(long)r * ND + j] != 0 && rmb[r] != 0) ? 1 : 0;
    for (int c = 0; c < NCOL; c++) cnt += (cd[(long)c * ND + j] != 0 && cmb[c] != 0) ? 1 : 0;
    float add = (dmask[(long)b * ND + j] != 0) ? (float)cnt : 0.f;
    float tv = dcnum[(long)b * ND + j] + add;
    dcnum[(long)b * ND + j] = (tv >= 1.f) ? tv : 1.f;
}

// ============ gemm_info: M=64,N=512,K=512 -> transposed bf16 info planes [b][512][128] ============
__global__ __launch_bounds__(256) void gemm_info(
    const float* __restrict__ A, long sA,
    const float* __restrict__ W,
    unsigned short* __restrict__ ihiT, unsigned short* __restrict__ iloT, int hoff,
    const float* __restrict__ rowscale, float alpha)
{
    int b = blockIdx.z;
    int n0 = blockIdx.x * 64;
    __shared__ float As[32][68], Ws[32][68];
    float acc[4][4] = {};
    int tx = threadIdx.x & 15, ty = threadIdx.x >> 4;
    int lm = threadIdx.x >> 2, lk = (threadIdx.x & 3) * 8;
    const float* Ab = A + (long)b * sA;
    for (int k0 = 0; k0 < DIM; k0 += 32) {
        const float4* pa = (const float4*)(Ab + (long)lm * DIM + k0 + lk);
        float4 va0 = pa[0], va1 = pa[1];
        const float4* pw = (const float4*)(W + (long)(n0 + lm) * DIM + k0 + lk);
        float4 vw0 = pw[0], vw1 = pw[1];
        As[lk + 0][lm] = va0.x; As[lk + 1][lm] = va0.y; As[lk + 2][lm] = va0.z; As[lk + 3][lm] = va0.w;
        As[lk + 4][lm] = va1.x; As[lk + 5][lm] = va1.y; As[lk + 6][lm] = va1.z; As[lk + 7][lm] = va1.w;
        Ws[lk + 0][lm] = vw0.x; Ws[lk + 1][lm] = vw0.y; Ws[lk + 2][lm] = vw0.z; Ws[lk + 3][lm] = vw0.w;
        Ws[lk + 4][lm] = vw1.x; Ws[lk + 5][lm] = vw1.y; Ws[lk + 6][lm] = vw1.z; Ws[lk + 7][lm] = vw1.w;
        __syncthreads();
        #pragma unroll
        for (int kk = 0; kk < 32; kk++) {
            float4 av = *(const float4*)&As[kk][ty * 4];
            float4 wv = *(const float4*)&Ws[kk][tx * 4];
            float a[4] = {av.x, av.y, av.z, av.w};
            float w[4] = {wv.x, wv.y, wv.z, wv.w};
            #pragma unroll
            for (int mi = 0; mi < 4; mi++)
                #pragma unroll
                for (int ni = 0; ni < 4; ni++)
                    acc[mi][ni] += a[mi] * w[ni];
        }
        __syncthreads();
    }
    #pragma unroll
    for (int mi = 0; mi < 4; mi++) {
        int gm = ty * 4 + mi;
        float scv = alpha * rowscale[(long)b * 64 + gm];
        #pragma unroll
        for (int ni = 0; ni < 4; ni++) {
            float v = scv * acc[mi][ni];
            unsigned short hh, ll; bsplit(v, hh, ll);
            long off = ((long)b * DIM + n0 + tx * 4 + ni) * 128 + hoff + gm;
            ihiT[off] = hh; iloT[off] = ll;
        }
    }
}

// ============ gemm_head: M=64,N=K=512, epi: relu((acc + m*q)/num) ============
__global__ __launch_bounds__(256) void gemm_head(
    const float* __restrict__ A, long sA,
    const float* __restrict__ W,
    float* __restrict__ C, long sC,
    const int* __restrict__ mrow, const float* __restrict__ addvec,
    const float* __restrict__ rownum)
{
    int b = blockIdx.z;
    int n0 = blockIdx.x * 64;
    __shared__ float As[32][68], Ws[32][68];
    float acc[4][4] = {};
    int tx = threadIdx.x & 15, ty = threadIdx.x >> 4;
    int lm = threadIdx.x >> 2, lk = (threadIdx.x & 3) * 8;
    const float* Ab = A + (long)b * sA;
    for (int k0 = 0; k0 < DIM; k0 += 32) {
        const float4* pa = (const float4*)(Ab + (long)lm * DIM + k0 + lk);
        float4 va0 = pa[0], va1 = pa[1];
        const float4* pw = (const float4*)(W + (long)(n0 + lm) * DIM + k0 + lk);
        float4 vw0 = pw[0], vw1 = pw[1];
        As[lk + 0][lm] = va0.x; As[lk + 1][lm] = va0.y; As[lk + 2][lm] = va0.z; As[lk + 3][lm] = va0.w;
        As[lk + 4][lm] = va1.x; As[lk + 5][lm] = va1.y; As[lk + 6][lm] = va1.z; As[lk + 7][lm] = va1.w;
        Ws[lk + 0][lm] = vw0.x; Ws[lk + 1][lm] = vw0.y; Ws[lk + 2][lm] = vw0.z; Ws[lk + 3][lm] = vw0.w;
        Ws[lk + 4][lm] = vw1.x; Ws[lk + 5][lm] = vw1.y; Ws[lk + 6][lm] = vw1.z; Ws[lk + 7][lm] = vw1.w;
        __syncthreads();
        #pragma unroll
        for (int kk = 0; kk < 32; kk++) {
            float4 av = *(const float4*)&As[kk][ty * 4];
            float4 wv = *(const float4*)&Ws[kk][tx * 4];
            float a[4] = {av.x, av.y, av.z, av.w};
            float w[4] = {wv.x, wv.y, wv.z, wv.w};
            #pragma unroll
            for (int mi = 0; mi < 4; mi++)
                #pragma unroll
                for (int ni = 0; ni < 4; ni++)
                    acc[mi][ni] += a[mi] * w[ni];
        }
        __syncthreads();
    }
    #pragma unroll
    for (int mi = 0; mi < 4; mi++) {
        int gm = ty * 4 + mi;
        float mq = (mrow[(long)b * 64 + gm] != 0) ? 1.f : 0.f;
        float inv = 1.f / rownum[(long)b * 64 + gm];
        float4 o;
        float* vo = (float*)&o;
        #pragma unroll
        for (int ni = 0; ni < 4; ni++) {
            float tv = (acc[mi][ni] + mq * addvec[(long)b * DIM + n0 + tx * 4 + ni]) * inv;
            vo[ni] = fmaxf(tv, 0.f);
        }
        *(float4*)(C + (long)b * sC + (long)gm * DIM + n0 + tx * 4) = o;
    }
}

// ============ pre_r/pre_c via MFMA: [rel_rd ; rel_cd] (128x2048) @ dcsum (2048x512) ============
__global__ __launch_bounds__(256) void k_pre_rc_mfma(
    const int* __restrict__ rel_rd, const int* __restrict__ rel_cd,
    const unsigned short* __restrict__ thi, const unsigned short* __restrict__ tlo,
    const int* __restrict__ rm, const int* __restrict__ cm,
    float* __restrict__ pre_r, float* __restrict__ pre_c)
{
    int b = blockIdx.y, n0 = blockIdx.x * 64;
    __shared__ unsigned short Aexp[128 * 64];
    __shared__ unsigned short Bhi[64 * 64], Blo[64 * 64];
    int tid = threadIdx.x, lane = tid & 63, wid = tid >> 6;
    int wm = wid >> 1, wn = wid & 1;
    int arow = tid >> 1, aseg = tid & 1;
    const int* relrow = (arow < 64)
        ? rel_rd + ((long)b * 64 + arow) * ND
        : rel_cd + ((long)b * 64 + arow - 64) * ND;
    int bn = tid >> 2, bq = tid & 3;
    const unsigned short* bsrc_h = thi + ((long)b * DIM + n0 + bn) * ND;
    const unsigned short* bsrc_l = tlo + ((long)b * DIM + n0 + bn) * ND;

    f32x4 acc[4][2];
    #pragma unroll
    for (int i = 0; i < 4; i++)
        #pragma unroll
        for (int j = 0; j < 2; j++)
            acc[i][j] = (f32x4){0.f, 0.f, 0.f, 0.f};

    for (int k0 = 0; k0 < ND; k0 += 64) {
        {
            const int4* pa = (const int4*)(relrow + k0 + aseg * 32);
            #pragma unroll
            for (int p = 0; p < 4; p++) {
                int4 v0 = pa[2 * p], v1 = pa[2 * p + 1];
                uint4 qv;
                qv.x = (v0.x ? 0x3F80u : 0u) | (v0.y ? 0x3F800000u : 0u);
                qv.y = (v0.z ? 0x3F80u : 0u) | (v0.w ? 0x3F800000u : 0u);
                qv.z = (v1.x ? 0x3F80u : 0u) | (v1.y ? 0x3F800000u : 0u);
                qv.w = (v1.z ? 0x3F80u : 0u) | (v1.w ? 0x3F800000u : 0u);
                int c = (aseg * 4 + p) ^ (arow & 7);
                *(uint4*)((char*)Aexp + arow * 128 + c * 16) = qv;
            }
        }
        {
            const uint4* ph = (const uint4*)(bsrc_h + k0 + bq * 16);
            const uint4* pl = (const uint4*)(bsrc_l + k0 + bq * 16);
            #pragma unroll
            for (int s = 0; s < 2; s++) {
                int c = (bq * 2 + s) ^ (bn & 7);
                *(uint4*)((char*)Bhi + bn * 128 + c * 16) = ph[s];
                *(uint4*)((char*)Blo + bn * 128 + c * 16) = pl[s];
            }
        }
        __syncthreads();
        #pragma unroll
        for (int ks = 0; ks < 2; ks++) {
            bf16x8 af[4], bh[2], bl[2];
            #pragma unroll
            for (int i = 0; i < 4; i++) {
                int rr = wm * 64 + i * 16 + (lane & 15);
                int cc = (ks * 4 + (lane >> 4)) ^ (rr & 7);
                af[i] = *(bf16x8*)((char*)Aexp + rr * 128 + cc * 16);
            }
            #pragma unroll
            for (int i = 0; i < 2; i++) {
                int nn = wn * 32 + i * 16 + (lane & 15);
                int c2 = (ks * 4 + (lane >> 4)) ^ (nn & 7);
                bh[i] = *(bf16x8*)((char*)Bhi + nn * 128 + c2 * 16);
                bl[i] = *(bf16x8*)((char*)Blo + nn * 128 + c2 * 16);
            }
            #pragma unroll
            for (int mi = 0; mi < 4; mi++)
                #pragma unroll
                for (int ni = 0; ni < 2; ni++) {
                    acc[mi][ni] = __builtin_amdgcn_mfma_f32_16x16x32_bf16(af[mi], bh[ni], acc[mi][ni], 0, 0, 0);
                    acc[mi][ni] = __builtin_amdgcn_mfma_f32_16x16x32_bf16(af[mi], bl[ni], acc[mi][ni], 0, 0, 0);
                }
        }
        __syncthreads();
    }
    const int* msk = wm ? cm : rm;
    float* outp = wm ? pre_c : pre_r;
    #pragma unroll
    for (int mi = 0; mi < 4; mi++) {
        int grow = mi * 16 + (lane >> 4) * 4;
        #pragma unroll
        for (int ni = 0; ni < 2; ni++) {
            int gcol = n0 + wn * 32 + ni * 16 + (lane & 15);
            #pragma unroll
            for (int r = 0; r < 4; r++) {
                int rrow = grow + r;
                float scv = (msk[b * 64 + rrow] != 0) ? 1.f : 0.f;
                outp[((long)b * 64 + rrow) * DIM + gcol] = scv * acc[mi][ni][r];
            }
        }
    }
}

// ============ projT = Wsr-split @ dcs-split^T via MFMA; gload_lds staging, direct-store epilogue ============
__global__ __launch_bounds__(256) void k_proj_mfma(
    const unsigned short* __restrict__ whi, const unsigned short* __restrict__ wlo,
    const unsigned short* __restrict__ dhi, const unsigned short* __restrict__ dlo,
    unsigned short* __restrict__ phi, unsigned short* __restrict__ plo)
{
    int flat = blockIdx.x;                   // 1024 blocks
    int tile = (flat & 7) * 128 + (flat >> 3);
    int b = tile >> 6;
    int rem = tile & 63;
    int m0 = (rem >> 4) * 128;
    int n0 = (rem & 15) * 128;

    __shared__ unsigned short Ahi[128 * 64], Alo[128 * 64];
    __shared__ unsigned short Bhi[128 * 64], Blo[128 * 64];

    int tid = threadIdx.x;
    int lane = tid & 63, wid = tid >> 6;
    int wm = wid >> 1, wn = wid & 1;

    // per-lane pre-swizzled source offsets (u16 elems) for linear chunk L = u2*256 + wid*64 + lane
    long ro0, ro1, ro2, ro3;
    {
        int L = wid * 64 + lane;
        int n = L >> 3, cg = (L & 7) ^ (n & 7);
        ro0 = (long)n * DIM + cg * 8;
        L += 256; n = L >> 3; cg = (L & 7) ^ (n & 7);
        ro1 = (long)n * DIM + cg * 8;
        L += 256; n = L >> 3; cg = (L & 7) ^ (n & 7);
        ro2 = (long)n * DIM + cg * 8;
        L += 256; n = L >> 3; cg = (L & 7) ^ (n & 7);
        ro3 = (long)n * DIM + cg * 8;
    }
    const unsigned short* wh_b = whi + (long)m0 * DIM;
    const unsigned short* wl_b = wlo + (long)m0 * DIM;
    const unsigned short* dh_b = dhi + ((long)b * ND + n0) * DIM;
    const unsigned short* dl_b = dlo + ((long)b * ND + n0) * DIM;
    int lb0 = (wid * 64) * 8, lb1 = (256 + wid * 64) * 8,
        lb2 = (512 + wid * 64) * 8, lb3 = (768 + wid * 64) * 8;

    f32x4 acc[4][4];
    #pragma unroll
    for (int i = 0; i < 4; i++)
        #pragma unroll
        for (int j = 0; j < 4; j++)
            acc[i][j] = (f32x4){0.f, 0.f, 0.f, 0.f};

    for (int k0 = 0; k0 < DIM; k0 += 64) {
        GLD(wh_b + ro0 + k0, Ahi + lb0); GLD(wh_b + ro1 + k0, Ahi + lb1);
        GLD(wh_b + ro2 + k0, Ahi + lb2); GLD(wh_b + ro3 + k0, Ahi + lb3);
        GLD(wl_b + ro0 + k0, Alo + lb0); GLD(wl_b + ro1 + k0, Alo + lb1);
        GLD(wl_b + ro2 + k0, Alo + lb2); GLD(wl_b + ro3 + k0, Alo + lb3);
        GLD(dh_b + ro0 + k0, Bhi + lb0); GLD(dh_b + ro1 + k0, Bhi + lb1);
        GLD(dh_b + ro2 + k0, Bhi + lb2); GLD(dh_b + ro3 + k0, Bhi + lb3);
        GLD(dl_b + ro0 + k0, Blo + lb0); GLD(dl_b + ro1 + k0, Blo + lb1);
        GLD(dl_b + ro2 + k0, Blo + lb2); GLD(dl_b + ro3 + k0, Blo + lb3);
        __syncthreads();
        #pragma unroll
        for (int ks = 0; ks < 2; ks++) {
            bf16x8 ah[4], al[4], bh[4], bl[4];
            #pragma unroll
            for (int i = 0; i < 4; i++) {
                int rr = wm * 64 + i * 16 + (lane & 15);
                int cc = (ks * 4 + (lane >> 4)) ^ (rr & 7);
                ah[i] = *(bf16x8*)((char*)Ahi + rr * 128 + cc * 16);
                al[i] = *(bf16x8*)((char*)Alo + rr * 128 + cc * 16);
                int nn = wn * 64 + i * 16 + (lane & 15);
                int c2 = (ks * 4 + (lane >> 4)) ^ (nn & 7);
                bh[i] = *(bf16x8*)((char*)Bhi + nn * 128 + c2 * 16);
                bl[i] = *(bf16x8*)((char*)Blo + nn * 128 + c2 * 16);
            }
            #pragma unroll
            for (int mi = 0; mi < 4; mi++)
                #pragma unroll
                for (int ni = 0; ni < 4; ni++) {
                    acc[mi][ni] = __builtin_amdgcn_mfma_f32_16x16x32_bf16(ah[mi], bh[ni], acc[mi][ni], 0, 0, 0);
                    acc[mi][ni] = __builtin_amdgcn_mfma_f32_16x16x32_bf16(ah[mi], bl[ni], acc[mi][ni], 0, 0, 0);
                    acc[mi][ni] = __builtin_amdgcn_mfma_f32_16x16x32_bf16(al[mi], bh[ni], acc[mi][ni], 0, 0, 0);
                }
        }
        __syncthreads();
    }
    #pragma unroll
    for (int mi = 0; mi < 4; mi++) {
        int grow = m0 + wm * 64 + mi * 16 + (lane >> 4) * 4;
        #pragma unroll
        for (int ni = 0; ni < 4; ni++) {
            int gcol = n0 + wn * 64 + ni * 16 + (lane & 15);
            #pragma unroll
            for (int r = 0; r < 4; r++) {
                unsigned short hh, ll; bsplit(acc[mi][ni][r], hh, ll);
                long off = ((long)b * DIM + grow + r) * ND + gcol;
                phi[off] = hh; plo[off] = ll;
            }
        }
    }
}

// ============ final dc: relu((bits @ (phi+plo) + rel^T @ info) / dc_num) ============
__global__ __launch_bounds__(256) void k_agg_final(
    const unsigned* __restrict__ bits,
    const unsigned short* __restrict__ phi, const unsigned short* __restrict__ plo,
    const unsigned short* __restrict__ ihiT, const unsigned short* __restrict__ iloT,
    const int* __restrict__ rel_rd, const int* __restrict__ rel_cd,
    const int* __restrict__ dmask, const float* __restrict__ rownum,
    float* __restrict__ out)
{
    int flat = blockIdx.x;
    int tile = (flat & 7) * 128 + (flat >> 3);
    int b = tile >> 6;
    int m0 = ((tile >> 2) & 15) * 128;
    int n0 = (tile & 3) * 128;

    __shared__ unsigned short Aexp[128 * 64];
    __shared__ unsigned short Bhi[128 * 64];
    __shared__ unsigned short Blo[128 * 64];
    __shared__ unsigned short dmu[128];
    __shared__ unsigned LDSw[256];

    int tid = threadIdx.x;
    int lane = tid & 63, wid = tid >> 6;
    int wm = wid >> 1, wn = wid & 1;

    if (tid < 128) dmu[tid] = (dmask[(long)b * ND + m0 + tid] != 0) ? (unsigned short)0x3F80 : (unsigned short)0;

    int arow = tid >> 1, awsel = tid & 1;
    const unsigned* abit_base = bits + ((long)b * ND + m0 + arow) * 64 + awsel;
    char* adst = (char*)Aexp + arow * 128;

    // per-lane pre-swizzled B-source offsets (u16 elems): linear chunk L = u2*256 + wid*64 + lane
    long bo0, bo1, bo2, bo3;         // main loop (row stride ND)
    long io0, io1, io2, io3;         // info tiles (row stride 128)
    {
        int L = wid * 64 + lane;
        int n = L >> 3, cg = (L & 7) ^ (n & 7);
        bo0 = (long)n * ND + cg * 8;  io0 = (long)n * 128 + cg * 8;
        L += 256; n = L >> 3; cg = (L & 7) ^ (n & 7);
        bo1 = (long)n * ND + cg * 8;  io1 = (long)n * 128 + cg * 8;
        L += 256; n = L >> 3; cg = (L & 7) ^ (n & 7);
        bo2 = (long)n * ND + cg * 8;  io2 = (long)n * 128 + cg * 8;
        L += 256; n = L >> 3; cg = (L & 7) ^ (n & 7);
        bo3 = (long)n * ND + cg * 8;  io3 = (long)n * 128 + cg * 8;
    }
    const unsigned short* ph_b = phi + ((long)b * DIM + n0) * ND;
    const unsigned short* pl_b = plo + ((long)b * DIM + n0) * ND;
    int lb0 = (wid * 64) * 8, lb1 = (256 + wid * 64) * 8,
        lb2 = (512 + wid * 64) * 8, lb3 = (768 + wid * 64) * 8;

    f32x4 acc[4][4];
    #pragma unroll
    for (int i = 0; i < 4; i++)
        #pragma unroll
        for (int j = 0; j < 4; j++)
            acc[i][j] = (f32x4){0.f, 0.f, 0.f, 0.f};

    // ---- main loop: 32 K-tiles over graph bits x proj planes ----
    for (int k0 = 0; k0 < ND; k0 += 64) {
        GLD(ph_b + bo0 + k0, Bhi + lb0); GLD(ph_b + bo1 + k0, Bhi + lb1);
        GLD(ph_b + bo2 + k0, Bhi + lb2); GLD(ph_b + bo3 + k0, Bhi + lb3);
        GLD(pl_b + bo0 + k0, Blo + lb0); GLD(pl_b + bo1 + k0, Blo + lb1);
        GLD(pl_b + bo2 + k0, Blo + lb2); GLD(pl_b + bo3 + k0, Blo + lb3);
        {
            unsigned w = abit_base[k0 >> 5];
            #pragma unroll
            for (int c = 0; c < 4; c++) {
                uint4 qv;
                qv.x = (((w >> (c * 8 + 0)) & 1u) ? 0x3F80u : 0u) | (((w >> (c * 8 + 1)) & 1u) ? 0x3F800000u : 0u);
                qv.y = (((w >> (c * 8 + 2)) & 1u) ? 0x3F80u : 0u) | (((w >> (c * 8 + 3)) & 1u) ? 0x3F800000u : 0u);
                qv.z = (((w >> (c * 8 + 4)) & 1u) ? 0x3F80u : 0u) | (((w >> (c * 8 + 5)) & 1u) ? 0x3F800000u : 0u);
                qv.w = (((w >> (c * 8 + 6)) & 1u) ? 0x3F80u : 0u) | (((w >> (c * 8 + 7)) & 1u) ? 0x3F800000u : 0u);
                int chunk = (awsel * 4 + c) ^ (arow & 7);
                *(uint4*)(adst + chunk * 16) = qv;
            }
        }
        __syncthreads();
        mfma_phase2(Aexp, Bhi, Blo, wm, wn, lane, acc);
        __syncthreads();
    }
    // ---- fused header-info tiles: 2 x K=64 over rel^T x infoT planes ----
    #pragma unroll
    for (int kt = 0; kt < 2; kt++) {
        const unsigned short* ih_b = ihiT + ((long)b * DIM + n0) * 128 + kt * 64;
        const unsigned short* il_b = iloT + ((long)b * DIM + n0) * 128 + kt * 64;
        GLD(ih_b + io0, Bhi + lb0); GLD(ih_b + io1, Bhi + lb1);
        GLD(ih_b + io2, Bhi + lb2); GLD(ih_b + io3, Bhi + lb3);
        GLD(il_b + io0, Blo + lb0); GLD(il_b + io1, Blo + lb1);
        GLD(il_b + io2, Blo + lb2); GLD(il_b + io3, Blo + lb3);
        const int* relrow = (kt ? rel_cd : rel_rd) + ((long)b * 64 + lane) * ND + m0 + wid * 32;
        #pragma unroll
        for (int c4 = 0; c4 < 32; c4 += 4) {
            int4 v = *(const int4*)(relrow + c4);
            unsigned long long mm;
            mm = __ballot(v.x != 0);
            if ((lane >> 1) == c4 + 0) LDSw[(wid * 32 + c4 + 0) * 2 + (lane & 1)] = (unsigned)(mm >> ((lane & 1) * 32));
            mm = __ballot(v.y != 0);
            if ((lane >> 1) == c4 + 1) LDSw[(wid * 32 + c4 + 1) * 2 + (lane & 1)] = (unsigned)(mm >> ((lane & 1) * 32));
            mm = __ballot(v.z != 0);
            if ((lane >> 1) == c4 + 2) LDSw[(wid * 32 + c4 + 2) * 2 + (lane & 1)] = (unsigned)(mm >> ((lane & 1) * 32));
            mm = __ballot(v.w != 0);
            if ((lane >> 1) == c4 + 3) LDSw[(wid * 32 + c4 + 3) * 2 + (lane & 1)] = (unsigned)(mm >> ((lane & 1) * 32));
        }
        __syncthreads();
        {
            unsigned w = LDSw[arow * 2 + awsel];
            unsigned dv = (unsigned)dmu[arow];
            unsigned dvh = dv << 16;
            #pragma unroll
            for (int c = 0; c < 4; c++) {
                uint4 qv;
                qv.x = (((w >> (c * 8 + 0)) & 1u) ? dv : 0u) | (((w >> (c * 8 + 1)) & 1u) ? dvh : 0u);
                qv.y = (((w >> (c * 8 + 2)) & 1u) ? dv : 0u) | (((w >> (c * 8 + 3)) & 1u) ? dvh : 0u);
                qv.z = (((w >> (c * 8 + 4)) & 1u) ? dv : 0u) | (((w >> (c * 8 + 5)) & 1u) ? dvh : 0u);
                qv.w = (((w >> (c * 8 + 6)) & 1u) ? dv : 0u) | (((w >> (c * 8 + 7)) & 1u) ? dvh : 0u);
                int chunk = (awsel * 4 + c) ^ (arow & 7);
                *(uint4*)(adst + chunk * 16) = qv;
            }
        }
        __syncthreads();
        mfma_phase2(Aexp, Bhi, Blo, wm, wn, lane, acc);
        __syncthreads();
    }
    // ---- epilogue ----
    #pragma unroll
    for (int mi = 0; mi < 4; mi++) {
        int grow = m0 + wm * 64 + mi * 16 + (lane >> 4) * 4;
        float inv[4];
        #pragma unroll
        for (int r = 0; r < 4; r++) inv[r] = 1.f / rownum[(long)b * ND + grow + r];
        #pragma unroll
        for (int ni = 0; ni < 4; ni++) {
            int gcol = n0 + wn * 64 + ni * 16 + (lane & 15);
            #pragma unroll
            for (int r = 0; r < 4; r++) {
                long off = ((long)b * ND + grow + r) * DIM + gcol;
                out[off] = fmaxf(acc[mi][ni][r] * inv[r], 0.f);
            }
        }
    }
}

// ==================================================================================
extern "C" void kernel_launch(void* const* d_in, const int* in_sizes, int n_in,
                              void* d_out, int out_size, void* d_ws, size_t ws_size,
                              hipStream_t stream)
{
    const float* q       = (const float*)d_in[0];
    const float* rh0     = (const float*)d_in[1];
    const float* ch0     = (const float*)d_in[2];
    const float* dc0     = (const float*)d_in[3];
    const int*   rm      = (const int*)d_in[4];
    const int*   cm      = (const int*)d_in[5];
    const int*   dmask   = (const int*)d_in[6];
    const int*   same_row= (const int*)d_in[7];
    const int*   same_col= (const int*)d_in[8];
    const int*   rel_rd  = (const int*)d_in[9];
    const int*   rel_cd  = (const int*)d_in[10];
    const float* wnode   = (const float*)d_in[11];
    const float* w_rdc   = (const float*)d_in[12];
    const float* w_cdc   = (const float*)d_in[13];
    const float* w_dcr   = (const float*)d_in[14];
    const float* w_dcc   = (const float*)d_in[15];
    const float* w_sr    = (const float*)d_in[16];
    const float* w_rq    = (const float*)d_in[18];
    const float* w_cq    = (const float*)d_in[19];

    float* out = (float*)d_out;
    float* rh = out;                           // [16,64,512]
    float* ch = out + (long)NB * NR * DIM;     // [16,64,512]
    float* dc = out + (long)NB * NR * DIM * 2; // [16,2048,512]

    if (ws_size < (size_t)WS_FLOATS * 4) return;

    float* ws      = (float*)d_ws;
    float* rh_num  = ws + OFF_RHNUM;
    float* ch_num  = ws + OFF_CHNUM;
    float* dc_num  = ws + OFF_DCNUM;
    float* rh_w    = ws + OFF_RHW;
    float* ch_w    = ws + OFF_CHW;
    float* qrow    = ws + OFF_QROW;
    float* qcol    = ws + OFF_QCOL;
    float* pre_r   = ws + OFF_PRER;
    float* pre_c   = ws + OFF_PREC;
    unsigned short* ihiT = (unsigned short*)(ws + OFF_INFORC);  // [16][512][128]
    unsigned short* iloT = ihiT + (size_t)NB * DIM * 128;
    unsigned* bits = (unsigned*)(ws + OFF_BITS);
    unsigned short* dhi = (unsigned short*)(ws + OFF_DCS);
    unsigned short* dlo = dhi + (size_t)NB * ND * DIM;
    unsigned short* thi = (unsigned short*)(ws + OFF_PROJ);  // transposed dcs planes
    unsigned short* tlo = thi + (size_t)NB * DIM * ND;
    unsigned short* phi = (unsigned short*)(ws + OFF_PROJ);  // proj planes overwrite thi/tlo (dead)
    unsigned short* plo = phi + (size_t)NB * DIM * ND;
    // whi/wlo in out-dc slice (dead between k_split-read and k_agg_final-write)
    unsigned short* whi = (unsigned short*)dc;
    unsigned short* wlo = whi + (size_t)DIM * DIM;

    hipMemcpyAsync(rh, rh0, sizeof(float) * (size_t)NB * NR * DIM, hipMemcpyDeviceToDevice, stream);
    hipMemcpyAsync(ch, ch0, sizeof(float) * (size_t)NB * NCOL * DIM, hipMemcpyDeviceToDevice, stream);

    k_bits<<<NB * ND / 2, 256, 0, stream>>>(same_row, same_col, dmask, bits, dc_num);
    k_rcnum<<<512, 256, 0, stream>>>(rel_rd, rel_cd, rm, cm, dmask, rh_num, ch_num);
    k_dcnum_final<<<dim3(ND / 256, NB), 256, 0, stream>>>(rel_rd, rel_cd, rm, cm, dmask, dc_num);
    k_q<<<dim3(128, 2, NB), 256, 0, stream>>>(q, w_rq, w_cq, qrow, qcol);

    for (int it = 0; it < 2; it++) {
        k_gate_rc<<<512, 256, 0, stream>>>(rh, ch, rm, cm, wnode, rh_w, ch_w);
        k_split<<<dim3(128, NB), 256, 0, stream>>>(it == 0 ? dc0 : dc, wnode, dmask, dhi, dlo, thi, tlo);
        k_wsplit<<<128, 256, 0, stream>>>(w_sr, whi, wlo);
        gemm_info<<<dim3(8, 1, NB), 256, 0, stream>>>(rh, (long)NR * DIM, w_dcr,
            ihiT, iloT, 0, rh_w, 1.0f);
        gemm_info<<<dim3(8, 1, NB), 256, 0, stream>>>(ch, (long)NCOL * DIM, w_dcc,
            ihiT, iloT, 64, ch_w, 2.0f);
        k_pre_rc_mfma<<<dim3(8, NB), 256, 0, stream>>>(rel_rd, rel_cd, thi, tlo, rm, cm, pre_r, pre_c);
        k_proj_mfma<<<1024, 256, 0, stream>>>(whi, wlo, dhi, dlo, phi, plo);
        gemm_head<<<dim3(8, 1, NB), 256, 0, stream>>>(pre_r, (long)NR * DIM, w_rdc,
            rh, (long)NR * DIM, rm, qrow, rh_num);
        gemm_head<<<dim3(8, 1, NB), 256, 0, stream>>>(pre_c, (long)NCOL * DIM, w_cdc,
            ch, (long)NCOL * DIM, cm, qcol, ch_num);
        k_agg_final<<<1024, 256, 0, stream>>>(bits, phi, plo, ihiT, iloT,
            rel_rd, rel_cd, dmask, dc_num, dc);
    }
}

// Round 11
// 963.435 us; speedup vs baseline: 1.1884x; 1.1150x over previous
//
#include <hip/hip_runtime.h>
#include <math.h>

#define NB 16
#define NR 64
#define NCOL 64
#define ND 2048
#define DIM 512

typedef __attribute__((ext_vector_type(4))) float f32x4;
typedef __attribute__((ext_vector_type(8))) short bf16x8;
typedef __attribute__((ext_vector_type(8))) unsigned short us8;

// async global->LDS, 16B per lane, linear LDS dest (wave-uniform base + lane*16)
#define GLD(src, dst) __builtin_amdgcn_global_load_lds( \
    (const __attribute__((address_space(1))) void*)(src), \
    (__attribute__((address_space(3))) void*)(dst), 16, 0, 0)

// ---------------- workspace layout (float offsets) ----------------
#define OFF_RHNUM  0L
#define OFF_CHNUM  1024L
#define OFF_DCNUM  2048L
#define OFF_QROW   36864L
#define OFF_QCOL   45056L
#define OFF_PRER   53248L
#define OFF_PREC   577536L
#define OFF_INFORC 1101824L   // ihiT/iloT bf16 info planes [b][512][128] (4 MB)
#define OFF_BITS   2150400L
#define OFF_DCS    4247552L   // dhi/dlo row-major planes
#define OFF_PROJ   21024768L  // thi/tlo transposed dcs planes, then phi/plo proj planes
#define WS_FLOATS  37801984L  // 151.2 MB
// whi/wlo live in the out-dc slice (dead mid-iteration)

// RNE fp32 -> bf16 split: v ~= hi + lo, both bf16
__device__ inline void bsplit(float v, unsigned short& h, unsigned short& l) {
    unsigned uv = __float_as_uint(v);
    unsigned hb = (uv + 0x7FFFu + ((uv >> 16) & 1u)) >> 16;
    h = (unsigned short)hb;
    float lo = v - __uint_as_float(hb << 16);
    unsigned lv = __float_as_uint(lo);
    l = (unsigned short)((lv + 0x7FFFu + ((lv >> 16) & 1u)) >> 16);
}

// spread 8 bits to every 4th position of a 32-bit word
__device__ inline unsigned spread4(unsigned x) {
    x = (x | (x << 12)) & 0x000F000Fu;
    x = (x | (x << 6))  & 0x03030303u;
    x = (x | (x << 3))  & 0x11111111u;
    return x;
}

// shared MFMA phase: 2 ks x (4x4) x 2 products (A exact, B hi+lo)
__device__ inline void mfma_phase2(const unsigned short* Aexp, const unsigned short* Bhi,
                                   const unsigned short* Blo, int wm, int wn, int lane,
                                   f32x4 acc[4][4])
{
    #pragma unroll
    for (int ks = 0; ks < 2; ks++) {
        bf16x8 af[4], bh[4], bl[4];
        #pragma unroll
        for (int i = 0; i < 4; i++) {
            int rr = wm * 64 + i * 16 + (lane & 15);
            int cc = (ks * 4 + (lane >> 4)) ^ (rr & 7);
            af[i] = *(const bf16x8*)((const char*)Aexp + rr * 128 + cc * 16);
            int nn = wn * 64 + i * 16 + (lane & 15);
            int c2 = (ks * 4 + (lane >> 4)) ^ (nn & 7);
            bh[i] = *(const bf16x8*)((const char*)Bhi + nn * 128 + c2 * 16);
            bl[i] = *(const bf16x8*)((const char*)Blo + nn * 128 + c2 * 16);
        }
        #pragma unroll
        for (int mi = 0; mi < 4; mi++)
            #pragma unroll
            for (int ni = 0; ni < 4; ni++) {
                acc[mi][ni] = __builtin_amdgcn_mfma_f32_16x16x32_bf16(af[mi], bh[ni], acc[mi][ni], 0, 0, 0);
                acc[mi][ni] = __builtin_amdgcn_mfma_f32_16x16x32_bf16(af[mi], bl[ni], acc[mi][ni], 0, 0, 0);
            }
    }
}

// ============ gate+split dc -> dhi/dlo [b][2048][512] AND thi/tlo [b][512][2048] ============
__global__ __launch_bounds__(256) void k_split(
    const float* __restrict__ src, const float* __restrict__ wnode, const int* __restrict__ dmask,
    unsigned short* __restrict__ dhi, unsigned short* __restrict__ dlo,
    unsigned short* __restrict__ thi, unsigned short* __restrict__ tlo)
{
    int b = blockIdx.y, j0 = blockIdx.x * 16;
    __shared__ float X[16 * 512];
    __shared__ float scs[16];
    int t = threadIdx.x;
    int r = t >> 4, u = t & 15;
    const float* row = src + ((long)b * ND + j0 + r) * DIM;
    float part = 0.f;
    #pragma unroll
    for (int i = 0; i < 8; i++) {
        int col = i * 64 + u * 4;
        float4 v = *(const float4*)(row + col);
        float4 w = *(const float4*)(wnode + col);
        part += v.x * w.x + v.y * w.y + v.z * w.z + v.w * w.w;
        *(float4*)&X[r * 512 + (col ^ ((r & 7) * 4))] = v;
    }
    part += __shfl_xor(part, 1, 64);
    part += __shfl_xor(part, 2, 64);
    part += __shfl_xor(part, 4, 64);
    part += __shfl_xor(part, 8, 64);
    if (u == 0) {
        float g = 1.f / (1.f + expf(-part));
        scs[r] = (dmask[(long)b * ND + j0 + r] != 0) ? g : 0.f;
    }
    __syncthreads();
    // row-major planes
    {
        float s = scs[r];
        long ob = ((long)b * ND + j0 + r) * DIM + u * 32;
        #pragma unroll
        for (int g = 0; g < 4; g++) {
            us8 ph, pl;
            #pragma unroll
            for (int e = 0; e < 8; e++) {
                int cc = u * 32 + g * 8 + e;
                float v = X[r * 512 + (cc ^ ((r & 7) * 4))] * s;
                unsigned short hh, ll; bsplit(v, hh, ll);
                ph[e] = hh; pl[e] = ll;
            }
            *(us8*)(dhi + ob + g * 8) = ph;
            *(us8*)(dlo + ob + g * 8) = pl;
        }
    }
    // transposed planes
    #pragma unroll
    for (int h = 0; h < 2; h++) {
        int n = t + h * 256;
        us8 ph0, ph1, pl0, pl1;
        #pragma unroll
        for (int rr = 0; rr < 16; rr++) {
            float v = X[rr * 512 + (n ^ ((rr & 7) * 4))] * scs[rr];
            unsigned short hh, ll; bsplit(v, hh, ll);
            if (rr < 8) { ph0[rr] = hh; pl0[rr] = ll; }
            else        { ph1[rr - 8] = hh; pl1[rr - 8] = ll; }
        }
        long ob = ((long)b * DIM + n) * ND + j0;
        *(us8*)(thi + ob) = ph0; *(us8*)(thi + ob + 8) = ph1;
        *(us8*)(tlo + ob) = pl0; *(us8*)(tlo + ob + 8) = pl1;
    }
}

// ============ split w_sr -> whi/wlo bf16 [512][512] ============
__global__ __launch_bounds__(256) void k_wsplit(
    const float* __restrict__ w, unsigned short* __restrict__ whi, unsigned short* __restrict__ wlo)
{
    long i = ((long)blockIdx.x * 256 + threadIdx.x) * 8;
    float4 a = *(const float4*)(w + i), b4 = *(const float4*)(w + i + 4);
    float v[8] = {a.x, a.y, a.z, a.w, b4.x, b4.y, b4.z, b4.w};
    us8 ph, pl;
    #pragma unroll
    for (int t = 0; t < 8; t++) {
        unsigned short hh, ll; bsplit(v[t], hh, ll);
        ph[t] = hh; pl[t] = ll;
    }
    *(us8*)(whi + i) = ph;
    *(us8*)(wlo + i) = pl;
}

// ============ q projections (once) ============
__global__ __launch_bounds__(256) void k_q(
    const float* __restrict__ q, const float* __restrict__ wrq, const float* __restrict__ wcq,
    float* __restrict__ qrow, float* __restrict__ qcol)
{
    int b = blockIdx.z;
    const float* W = blockIdx.y ? wcq : wrq;
    float* out = blockIdx.y ? qcol : qrow;
    int wave = threadIdx.x >> 6, lane = threadIdx.x & 63;
    int n = blockIdx.x * 4 + wave;
    const float4* qp = (const float4*)(q + (long)b * DIM);
    const float4* wp = (const float4*)(W + (long)n * DIM);
    float4 a0 = qp[lane * 2], a1 = qp[lane * 2 + 1];
    float4 w0 = wp[lane * 2], w1 = wp[lane * 2 + 1];
    float s = a0.x * w0.x + a0.y * w0.y + a0.z * w0.z + a0.w * w0.w
            + a1.x * w1.x + a1.y * w1.y + a1.z * w1.z + a1.w * w1.w;
    #pragma unroll
    for (int o = 32; o > 0; o >>= 1) s += __shfl_xor(s, o, 64);
    if (lane == 0) out[(long)b * DIM + n] = s;
}

// ============ pack same_row bits + partial dc_num: 2 rows/block, deep loads (R9) ============
__global__ __launch_bounds__(256) void k_bits(
    const int* __restrict__ sr, const int* __restrict__ sc, const int* __restrict__ dmask,
    unsigned* __restrict__ bits, float* __restrict__ dcnum)
{
    long bi0 = (long)blockIdx.x * 2;         // rows bi0, bi0+1 (same batch: ND even)
    int b = (int)(bi0 >> 11);
    int wave = threadIdx.x >> 6, lane = threadIdx.x & 63;
    const int4* dm4 = (const int4*)(dmask + (long)b * ND);
    int4 vs[2][2], vc[2][2], vd[2];
    #pragma unroll
    for (int h = 0; h < 2; h++) {
        int vidx = wave * 128 + h * 64 + lane;
        vd[h] = dm4[vidx];
        #pragma unroll
        for (int r = 0; r < 2; r++) {
            vs[r][h] = ((const int4*)(sr + (bi0 + r) * ND))[vidx];
            vc[r][h] = ((const int4*)(sc + (bi0 + r) * ND))[vidx];
        }
    }
    int dmi0 = dmask[bi0], dmi1 = dmask[bi0 + 1];
    __shared__ int red[2][4];
    #pragma unroll
    for (int r = 0; r < 2; r++) {
        int dmi = r ? dmi1 : dmi0;
        unsigned* brow = bits + (bi0 + r) * 64;
        int cnt = 0;
        #pragma unroll
        for (int h = 0; h < 2; h++) {
            int4 s4 = vs[r][h], c4 = vc[r][h], d4 = vd[h];
            bool d0 = dmi && d4.x, d1 = dmi && d4.y, d2 = dmi && d4.z, d3 = dmi && d4.w;
            unsigned long long m0 = __ballot(d0 && s4.x);
            unsigned long long m1 = __ballot(d1 && s4.y);
            unsigned long long m2 = __ballot(d2 && s4.z);
            unsigned long long m3 = __ballot(d3 && s4.w);
            unsigned long long n0 = __ballot(d0 && c4.x);
            unsigned long long n1 = __ballot(d1 && c4.y);
            unsigned long long n2 = __ballot(d2 && c4.z);
            unsigned long long n3 = __ballot(d3 && c4.w);
            cnt += __popcll(m0) + __popcll(m1) + __popcll(m2) + __popcll(m3)
                 + __popcll(n0) + __popcll(n1) + __popcll(n2) + __popcll(n3);
            if (lane < 8) {
                unsigned w = spread4((unsigned)(m0 >> (8 * lane)) & 0xFFu)
                           | (spread4((unsigned)(m1 >> (8 * lane)) & 0xFFu) << 1)
                           | (spread4((unsigned)(m2 >> (8 * lane)) & 0xFFu) << 2)
                           | (spread4((unsigned)(m3 >> (8 * lane)) & 0xFFu) << 3);
                brow[wave * 16 + h * 8 + lane] = w;
            }
        }
        if (lane == 0) red[r][wave] = cnt;
    }
    __syncthreads();
    if (threadIdx.x < 2) {
        int s = red[threadIdx.x][0] + red[threadIdx.x][1] + red[threadIdx.x][2] + red[threadIdx.x][3];
        dcnum[bi0 + threadIdx.x] = (float)s;
    }
}

// ============ rh_num / ch_num (R9) ============
__global__ __launch_bounds__(256) void k_rcnum(
    const int* __restrict__ rel_rd, const int* __restrict__ rel_cd,
    const int* __restrict__ rm, const int* __restrict__ cm, const int* __restrict__ dmask,
    float* __restrict__ rh_num, float* __restrict__ ch_num)
{
    int wave = threadIdx.x >> 6, lane = threadIdx.x & 63;
    long idx = (long)blockIdx.x * 4 + wave;  // < 2048
    const int* row; int mval; float* out; const int* dmb;
    if (idx < NB * NR) {
        int b = (int)(idx >> 6), r = (int)(idx & 63);
        row = rel_rd + ((long)b * NR + r) * ND; mval = rm[b * NR + r];
        out = rh_num + b * NR + r; dmb = dmask + (long)b * ND;
    } else {
        long tt = idx - NB * NR; int b = (int)(tt >> 6), c = (int)(tt & 63);
        row = rel_cd + ((long)b * NCOL + c) * ND; mval = cm[b * NCOL + c];
        out = ch_num + b * NCOL + c; dmb = dmask + (long)b * ND;
    }
    int cnt = 0;
    for (int rr = 0; rr < 32; rr++) {
        int j = rr * 64 + lane;
        cnt += (row[j] != 0 && dmb[j] != 0) ? 1 : 0;
    }
    #pragma unroll
    for (int o = 32; o > 0; o >>= 1) cnt += __shfl_xor(cnt, o, 64);
    if (lane == 0) {
        float s = mval ? (float)cnt : 0.f;
        *out = (s >= 1.f) ? (s + 1.f) : 1.f;
    }
}

// ============ finalize dc_num (R9) ============
__global__ __launch_bounds__(256) void k_dcnum_final(
    const int* __restrict__ rel_rd, const int* __restrict__ rel_cd,
    const int* __restrict__ rm, const int* __restrict__ cm, const int* __restrict__ dmask,
    float* __restrict__ dcnum)
{
    int b = blockIdx.y;
    int j = blockIdx.x * 256 + threadIdx.x;
    const int* rd = rel_rd + (long)b * NR * ND;
    const int* cd = rel_cd + (long)b * NCOL * ND;
    const int* rmb = rm + b * NR;
    const int* cmb = cm + b * NCOL;
    int cnt = 0;
    for (int r = 0; r < NR; r++)  cnt += (rd[(long)r * ND + j] != 0 && rmb[r] != 0) ? 1 : 0;
    for (int c = 0; c < NCOL; c++) cnt += (cd[(long)c * ND + j] != 0 && cmb[c] != 0) ? 1 : 0;
    float add = (dmask[(long)b * ND + j] != 0) ? (float)cnt : 0.f;
    float tv = dcnum[(long)b * ND + j] + add;
    dcnum[(long)b * ND + j] = (tv >= 1.f) ? tv : 1.f;
}

// ============ gemm_info2: gate-fused; y=0: rh/w_dcr (a=1,hoff=0), y=1: ch/w_dcc (a=2,hoff=64) ============
__global__ __launch_bounds__(256) void gemm_info2(
    const float* __restrict__ rh, const float* __restrict__ ch,
    const float* __restrict__ w_dcr, const float* __restrict__ w_dcc,
    const int* __restrict__ rm, const int* __restrict__ cm,
    const float* __restrict__ wnode,
    unsigned short* __restrict__ ihiT, unsigned short* __restrict__ iloT)
{
    int b = blockIdx.z, y = blockIdx.y;
    int n0 = blockIdx.x * 64;
    const float* Ab = (y ? ch : rh) + (long)b * 64 * DIM;
    const float* W = y ? w_dcc : w_dcr;
    const int* msk = (y ? cm : rm) + b * 64;
    float alpha = y ? 2.f : 1.f;
    int hoff = y ? 64 : 0;

    __shared__ float As[32][68], Ws[32][68];
    __shared__ float LDSg[64];
    int tid = threadIdx.x, wave = tid >> 6, lane = tid & 63;
    // ---- gate prologue: LDSg[row] = msk ? sigmoid(A[row].wnode) : 0 ----
    {
        const float4* pw = (const float4*)wnode;
        float4 wa = pw[lane * 2], wb = pw[lane * 2 + 1];
        for (int rr = 0; rr < 16; rr++) {
            int row = wave * 16 + rr;
            const float4* px = (const float4*)(Ab + (long)row * DIM);
            float4 xa = px[lane * 2], xb = px[lane * 2 + 1];
            float s = xa.x * wa.x + xa.y * wa.y + xa.z * wa.z + xa.w * wa.w
                    + xb.x * wb.x + xb.y * wb.y + xb.z * wb.z + xb.w * wb.w;
            #pragma unroll
            for (int o = 32; o > 0; o >>= 1) s += __shfl_xor(s, o, 64);
            if (lane == 0)
                LDSg[row] = (msk[row] != 0) ? 1.f / (1.f + expf(-s)) : 0.f;
        }
    }
    __syncthreads();

    float acc[4][4] = {};
    int tx = tid & 15, ty = tid >> 4;
    int lm = tid >> 2, lk = (tid & 3) * 8;
    for (int k0 = 0; k0 < DIM; k0 += 32) {
        const float4* pa = (const float4*)(Ab + (long)lm * DIM + k0 + lk);
        float4 va0 = pa[0], va1 = pa[1];
        const float4* pw = (const float4*)(W + (long)(n0 + lm) * DIM + k0 + lk);
        float4 vw0 = pw[0], vw1 = pw[1];
        As[lk + 0][lm] = va0.x; As[lk + 1][lm] = va0.y; As[lk + 2][lm] = va0.z; As[lk + 3][lm] = va0.w;
        As[lk + 4][lm] = va1.x; As[lk + 5][lm] = va1.y; As[lk + 6][lm] = va1.z; As[lk + 7][lm] = va1.w;
        Ws[lk + 0][lm] = vw0.x; Ws[lk + 1][lm] = vw0.y; Ws[lk + 2][lm] = vw0.z; Ws[lk + 3][lm] = vw0.w;
        Ws[lk + 4][lm] = vw1.x; Ws[lk + 5][lm] = vw1.y; Ws[lk + 6][lm] = vw1.z; Ws[lk + 7][lm] = vw1.w;
        __syncthreads();
        #pragma unroll
        for (int kk = 0; kk < 32; kk++) {
            float4 av = *(const float4*)&As[kk][ty * 4];
            float4 wv = *(const float4*)&Ws[kk][tx * 4];
            float a[4] = {av.x, av.y, av.z, av.w};
            float w[4] = {wv.x, wv.y, wv.z, wv.w};
            #pragma unroll
            for (int mi = 0; mi < 4; mi++)
                #pragma unroll
                for (int ni = 0; ni < 4; ni++)
                    acc[mi][ni] += a[mi] * w[ni];
        }
        __syncthreads();
    }
    #pragma unroll
    for (int mi = 0; mi < 4; mi++) {
        int gm = ty * 4 + mi;
        float scv = alpha * LDSg[gm];
        #pragma unroll
        for (int ni = 0; ni < 4; ni++) {
            float v = scv * acc[mi][ni];
            unsigned short hh, ll; bsplit(v, hh, ll);
            long off = ((long)b * DIM + n0 + tx * 4 + ni) * 128 + hoff + gm;
            ihiT[off] = hh; iloT[off] = ll;
        }
    }
}

// ============ gemm_head2: y=0: pre_r/w_rdc->rh, y=1: pre_c/w_cdc->ch ============
__global__ __launch_bounds__(256) void gemm_head2(
    const float* __restrict__ pre_r, const float* __restrict__ pre_c,
    const float* __restrict__ w_rdc, const float* __restrict__ w_cdc,
    float* __restrict__ rh, float* __restrict__ ch,
    const int* __restrict__ rm, const int* __restrict__ cm,
    const float* __restrict__ qrow, const float* __restrict__ qcol,
    const float* __restrict__ rh_num, const float* __restrict__ ch_num)
{
    int b = blockIdx.z, y = blockIdx.y;
    int n0 = blockIdx.x * 64;
    const float* Ab = (y ? pre_c : pre_r) + (long)b * 64 * DIM;
    const float* W = y ? w_cdc : w_rdc;
    float* C = (y ? ch : rh) + (long)b * 64 * DIM;
    const int* mrow = (y ? cm : rm) + b * 64;
    const float* addvec = (y ? qcol : qrow) + (long)b * DIM;
    const float* rownum = (y ? ch_num : rh_num) + b * 64;

    __shared__ float As[32][68], Ws[32][68];
    float acc[4][4] = {};
    int tx = threadIdx.x & 15, ty = threadIdx.x >> 4;
    int lm = threadIdx.x >> 2, lk = (threadIdx.x & 3) * 8;
    for (int k0 = 0; k0 < DIM; k0 += 32) {
        const float4* pa = (const float4*)(Ab + (long)lm * DIM + k0 + lk);
        float4 va0 = pa[0], va1 = pa[1];
        const float4* pw = (const float4*)(W + (long)(n0 + lm) * DIM + k0 + lk);
        float4 vw0 = pw[0], vw1 = pw[1];
        As[lk + 0][lm] = va0.x; As[lk + 1][lm] = va0.y; As[lk + 2][lm] = va0.z; As[lk + 3][lm] = va0.w;
        As[lk + 4][lm] = va1.x; As[lk + 5][lm] = va1.y; As[lk + 6][lm] = va1.z; As[lk + 7][lm] = va1.w;
        Ws[lk + 0][lm] = vw0.x; Ws[lk + 1][lm] = vw0.y; Ws[lk + 2][lm] = vw0.z; Ws[lk + 3][lm] = vw0.w;
        Ws[lk + 4][lm] = vw1.x; Ws[lk + 5][lm] = vw1.y; Ws[lk + 6][lm] = vw1.z; Ws[lk + 7][lm] = vw1.w;
        __syncthreads();
        #pragma unroll
        for (int kk = 0; kk < 32; kk++) {
            float4 av = *(const float4*)&As[kk][ty * 4];
            float4 wv = *(const float4*)&Ws[kk][tx * 4];
            float a[4] = {av.x, av.y, av.z, av.w};
            float w[4] = {wv.x, wv.y, wv.z, wv.w};
            #pragma unroll
            for (int mi = 0; mi < 4; mi++)
                #pragma unroll
                for (int ni = 0; ni < 4; ni++)
                    acc[mi][ni] += a[mi] * w[ni];
        }
        __syncthreads();
    }
    #pragma unroll
    for (int mi = 0; mi < 4; mi++) {
        int gm = ty * 4 + mi;
        float mq = (mrow[gm] != 0) ? 1.f : 0.f;
        float inv = 1.f / rownum[gm];
        float4 o;
        float* vo = (float*)&o;
        #pragma unroll
        for (int ni = 0; ni < 4; ni++) {
            float tv = (acc[mi][ni] + mq * addvec[n0 + tx * 4 + ni]) * inv;
            vo[ni] = fmaxf(tv, 0.f);
        }
        *(float4*)(C + (long)gm * DIM + n0 + tx * 4) = o;
    }
}

// ============ pre_r/pre_c via MFMA: [rel_rd ; rel_cd] (128x2048) @ dcsum (2048x512) ============
__global__ __launch_bounds__(256) void k_pre_rc_mfma(
    const int* __restrict__ rel_rd, const int* __restrict__ rel_cd,
    const unsigned short* __restrict__ thi, const unsigned short* __restrict__ tlo,
    const int* __restrict__ rm, const int* __restrict__ cm,
    float* __restrict__ pre_r, float* __restrict__ pre_c)
{
    int b = blockIdx.y, n0 = blockIdx.x * 64;
    __shared__ unsigned short Aexp[128 * 64];
    __shared__ unsigned short Bhi[64 * 64], Blo[64 * 64];
    int tid = threadIdx.x, lane = tid & 63, wid = tid >> 6;
    int wm = wid >> 1, wn = wid & 1;
    int arow = tid >> 1, aseg = tid & 1;
    const int* relrow = (arow < 64)
        ? rel_rd + ((long)b * 64 + arow) * ND
        : rel_cd + ((long)b * 64 + arow - 64) * ND;
    int bn = tid >> 2, bq = tid & 3;
    const unsigned short* bsrc_h = thi + ((long)b * DIM + n0 + bn) * ND;
    const unsigned short* bsrc_l = tlo + ((long)b * DIM + n0 + bn) * ND;

    f32x4 acc[4][2];
    #pragma unroll
    for (int i = 0; i < 4; i++)
        #pragma unroll
        for (int j = 0; j < 2; j++)
            acc[i][j] = (f32x4){0.f, 0.f, 0.f, 0.f};

    for (int k0 = 0; k0 < ND; k0 += 64) {
        {
            const int4* pa = (const int4*)(relrow + k0 + aseg * 32);
            #pragma unroll
            for (int p = 0; p < 4; p++) {
                int4 v0 = pa[2 * p], v1 = pa[2 * p + 1];
                uint4 qv;
                qv.x = (v0.x ? 0x3F80u : 0u) | (v0.y ? 0x3F800000u : 0u);
                qv.y = (v0.z ? 0x3F80u : 0u) | (v0.w ? 0x3F800000u : 0u);
                qv.z = (v1.x ? 0x3F80u : 0u) | (v1.y ? 0x3F800000u : 0u);
                qv.w = (v1.z ? 0x3F80u : 0u) | (v1.w ? 0x3F800000u : 0u);
                int c = (aseg * 4 + p) ^ (arow & 7);
                *(uint4*)((char*)Aexp + arow * 128 + c * 16) = qv;
            }
        }
        {
            const uint4* ph = (const uint4*)(bsrc_h + k0 + bq * 16);
            const uint4* pl = (const uint4*)(bsrc_l + k0 + bq * 16);
            #pragma unroll
            for (int s = 0; s < 2; s++) {
                int c = (bq * 2 + s) ^ (bn & 7);
                *(uint4*)((char*)Bhi + bn * 128 + c * 16) = ph[s];
                *(uint4*)((char*)Blo + bn * 128 + c * 16) = pl[s];
            }
        }
        __syncthreads();
        #pragma unroll
        for (int ks = 0; ks < 2; ks++) {
            bf16x8 af[4], bh[2], bl[2];
            #pragma unroll
            for (int i = 0; i < 4; i++) {
                int rr = wm * 64 + i * 16 + (lane & 15);
                int cc = (ks * 4 + (lane >> 4)) ^ (rr & 7);
                af[i] = *(bf16x8*)((char*)Aexp + rr * 128 + cc * 16);
            }
            #pragma unroll
            for (int i = 0; i < 2; i++) {
                int nn = wn * 32 + i * 16 + (lane & 15);
                int c2 = (ks * 4 + (lane >> 4)) ^ (nn & 7);
                bh[i] = *(bf16x8*)((char*)Bhi + nn * 128 + c2 * 16);
                bl[i] = *(bf16x8*)((char*)Blo + nn * 128 + c2 * 16);
            }
            #pragma unroll
            for (int mi = 0; mi < 4; mi++)
                #pragma unroll
                for (int ni = 0; ni < 2; ni++) {
                    acc[mi][ni] = __builtin_amdgcn_mfma_f32_16x16x32_bf16(af[mi], bh[ni], acc[mi][ni], 0, 0, 0);
                    acc[mi][ni] = __builtin_amdgcn_mfma_f32_16x16x32_bf16(af[mi], bl[ni], acc[mi][ni], 0, 0, 0);
                }
        }
        __syncthreads();
    }
    const int* msk = wm ? cm : rm;
    float* outp = wm ? pre_c : pre_r;
    #pragma unroll
    for (int mi = 0; mi < 4; mi++) {
        int grow = mi * 16 + (lane >> 4) * 4;
        #pragma unroll
        for (int ni = 0; ni < 2; ni++) {
            int gcol = n0 + wn * 32 + ni * 16 + (lane & 15);
            #pragma unroll
            for (int r = 0; r < 4; r++) {
                int rrow = grow + r;
                float scv = (msk[b * 64 + rrow] != 0) ? 1.f : 0.f;
                outp[((long)b * 64 + rrow) * DIM + gcol] = scv * acc[mi][ni][r];
            }
        }
    }
}

// ============ projT = Wsr-split @ dcs-split^T via MFMA; gload_lds staging ============
__global__ __launch_bounds__(256) void k_proj_mfma(
    const unsigned short* __restrict__ whi, const unsigned short* __restrict__ wlo,
    const unsigned short* __restrict__ dhi, const unsigned short* __restrict__ dlo,
    unsigned short* __restrict__ phi, unsigned short* __restrict__ plo)
{
    int flat = blockIdx.x;                   // 1024 blocks
    int tile = (flat & 7) * 128 + (flat >> 3);
    int b = tile >> 6;
    int rem = tile & 63;
    int m0 = (rem >> 4) * 128;
    int n0 = (rem & 15) * 128;

    __shared__ unsigned short Ahi[128 * 64], Alo[128 * 64];
    __shared__ unsigned short Bhi[128 * 64], Blo[128 * 64];

    int tid = threadIdx.x;
    int lane = tid & 63, wid = tid >> 6;
    int wm = wid >> 1, wn = wid & 1;

    long ro0, ro1, ro2, ro3;
    {
        int L = wid * 64 + lane;
        int n = L >> 3, cg = (L & 7) ^ (n & 7);
        ro0 = (long)n * DIM + cg * 8;
        L += 256; n = L >> 3; cg = (L & 7) ^ (n & 7);
        ro1 = (long)n * DIM + cg * 8;
        L += 256; n = L >> 3; cg = (L & 7) ^ (n & 7);
        ro2 = (long)n * DIM + cg * 8;
        L += 256; n = L >> 3; cg = (L & 7) ^ (n & 7);
        ro3 = (long)n * DIM + cg * 8;
    }
    const unsigned short* wh_b = whi + (long)m0 * DIM;
    const unsigned short* wl_b = wlo + (long)m0 * DIM;
    const unsigned short* dh_b = dhi + ((long)b * ND + n0) * DIM;
    const unsigned short* dl_b = dlo + ((long)b * ND + n0) * DIM;
    int lb0 = (wid * 64) * 8, lb1 = (256 + wid * 64) * 8,
        lb2 = (512 + wid * 64) * 8, lb3 = (768 + wid * 64) * 8;

    f32x4 acc[4][4];
    #pragma unroll
    for (int i = 0; i < 4; i++)
        #pragma unroll
        for (int j = 0; j < 4; j++)
            acc[i][j] = (f32x4){0.f, 0.f, 0.f, 0.f};

    for (int k0 = 0; k0 < DIM; k0 += 64) {
        GLD(wh_b + ro0 + k0, Ahi + lb0); GLD(wh_b + ro1 + k0, Ahi + lb1);
        GLD(wh_b + ro2 + k0, Ahi + lb2); GLD(wh_b + ro3 + k0, Ahi + lb3);
        GLD(wl_b + ro0 + k0, Alo + lb0); GLD(wl_b + ro1 + k0, Alo + lb1);
        GLD(wl_b + ro2 + k0, Alo + lb2); GLD(wl_b + ro3 + k0, Alo + lb3);
        GLD(dh_b + ro0 + k0, Bhi + lb0); GLD(dh_b + ro1 + k0, Bhi + lb1);
        GLD(dh_b + ro2 + k0, Bhi + lb2); GLD(dh_b + ro3 + k0, Bhi + lb3);
        GLD(dl_b + ro0 + k0, Blo + lb0); GLD(dl_b + ro1 + k0, Blo + lb1);
        GLD(dl_b + ro2 + k0, Blo + lb2); GLD(dl_b + ro3 + k0, Blo + lb3);
        __syncthreads();
        #pragma unroll
        for (int ks = 0; ks < 2; ks++) {
            bf16x8 ah[4], al[4], bh[4], bl[4];
            #pragma unroll
            for (int i = 0; i < 4; i++) {
                int rr = wm * 64 + i * 16 + (lane & 15);
                int cc = (ks * 4 + (lane >> 4)) ^ (rr & 7);
                ah[i] = *(bf16x8*)((char*)Ahi + rr * 128 + cc * 16);
                al[i] = *(bf16x8*)((char*)Alo + rr * 128 + cc * 16);
                int nn = wn * 64 + i * 16 + (lane & 15);
                int c2 = (ks * 4 + (lane >> 4)) ^ (nn & 7);
                bh[i] = *(bf16x8*)((char*)Bhi + nn * 128 + c2 * 16);
                bl[i] = *(bf16x8*)((char*)Blo + nn * 128 + c2 * 16);
            }
            #pragma unroll
            for (int mi = 0; mi < 4; mi++)
                #pragma unroll
                for (int ni = 0; ni < 4; ni++) {
                    acc[mi][ni] = __builtin_amdgcn_mfma_f32_16x16x32_bf16(ah[mi], bh[ni], acc[mi][ni], 0, 0, 0);
                    acc[mi][ni] = __builtin_amdgcn_mfma_f32_16x16x32_bf16(ah[mi], bl[ni], acc[mi][ni], 0, 0, 0);
                    acc[mi][ni] = __builtin_amdgcn_mfma_f32_16x16x32_bf16(al[mi], bh[ni], acc[mi][ni], 0, 0, 0);
                }
        }
        __syncthreads();
    }
    #pragma unroll
    for (int mi = 0; mi < 4; mi++) {
        int grow = m0 + wm * 64 + mi * 16 + (lane >> 4) * 4;
        #pragma unroll
        for (int ni = 0; ni < 4; ni++) {
            int gcol = n0 + wn * 64 + ni * 16 + (lane & 15);
            #pragma unroll
            for (int r = 0; r < 4; r++) {
                unsigned short hh, ll; bsplit(acc[mi][ni][r], hh, ll);
                long off = ((long)b * DIM + grow + r) * ND + gcol;
                phi[off] = hh; plo[off] = ll;
            }
        }
    }
}

// ============ final dc: relu((bits @ (phi+plo) + rel^T @ info) / dc_num) ============
__global__ __launch_bounds__(256) void k_agg_final(
    const unsigned* __restrict__ bits,
    const unsigned short* __restrict__ phi, const unsigned short* __restrict__ plo,
    const unsigned short* __restrict__ ihiT, const unsigned short* __restrict__ iloT,
    const int* __restrict__ rel_rd, const int* __restrict__ rel_cd,
    const int* __restrict__ dmask, const float* __restrict__ rownum,
    float* __restrict__ out)
{
    int flat = blockIdx.x;
    int tile = (flat & 7) * 128 + (flat >> 3);
    int b = tile >> 6;
    int m0 = ((tile >> 2) & 15) * 128;
    int n0 = (tile & 3) * 128;

    __shared__ unsigned short Aexp[128 * 64];
    __shared__ unsigned short Bhi[128 * 64];
    __shared__ unsigned short Blo[128 * 64];
    __shared__ unsigned short dmu[128];
    __shared__ unsigned LDSw[256];

    int tid = threadIdx.x;
    int lane = tid & 63, wid = tid >> 6;
    int wm = wid >> 1, wn = wid & 1;

    if (tid < 128) dmu[tid] = (dmask[(long)b * ND + m0 + tid] != 0) ? (unsigned short)0x3F80 : (unsigned short)0;

    int arow = tid >> 1, awsel = tid & 1;
    const unsigned* abit_base = bits + ((long)b * ND + m0 + arow) * 64 + awsel;
    char* adst = (char*)Aexp + arow * 128;

    long bo0, bo1, bo2, bo3;
    long io0, io1, io2, io3;
    {
        int L = wid * 64 + lane;
        int n = L >> 3, cg = (L & 7) ^ (n & 7);
        bo0 = (long)n * ND + cg * 8;  io0 = (long)n * 128 + cg * 8;
        L += 256; n = L >> 3; cg = (L & 7) ^ (n & 7);
        bo1 = (long)n * ND + cg * 8;  io1 = (long)n * 128 + cg * 8;
        L += 256; n = L >> 3; cg = (L & 7) ^ (n & 7);
        bo2 = (long)n * ND + cg * 8;  io2 = (long)n * 128 + cg * 8;
        L += 256; n = L >> 3; cg = (L & 7) ^ (n & 7);
        bo3 = (long)n * ND + cg * 8;  io3 = (long)n * 128 + cg * 8;
    }
    const unsigned short* ph_b = phi + ((long)b * DIM + n0) * ND;
    const unsigned short* pl_b = plo + ((long)b * DIM + n0) * ND;
    int lb0 = (wid * 64) * 8, lb1 = (256 + wid * 64) * 8,
        lb2 = (512 + wid * 64) * 8, lb3 = (768 + wid * 64) * 8;

    f32x4 acc[4][4];
    #pragma unroll
    for (int i = 0; i < 4; i++)
        #pragma unroll
        for (int j = 0; j < 4; j++)
            acc[i][j] = (f32x4){0.f, 0.f, 0.f, 0.f};

    // ---- main loop: 32 K-tiles over graph bits x proj planes ----
    for (int k0 = 0; k0 < ND; k0 += 64) {
        GLD(ph_b + bo0 + k0, Bhi + lb0); GLD(ph_b + bo1 + k0, Bhi + lb1);
        GLD(ph_b + bo2 + k0, Bhi + lb2); GLD(ph_b + bo3 + k0, Bhi + lb3);
        GLD(pl_b + bo0 + k0, Blo + lb0); GLD(pl_b + bo1 + k0, Blo + lb1);
        GLD(pl_b + bo2 + k0, Blo + lb2); GLD(pl_b + bo3 + k0, Blo + lb3);
        {
            unsigned w = abit_base[k0 >> 5];
            #pragma unroll
            for (int c = 0; c < 4; c++) {
                uint4 qv;
                qv.x = (((w >> (c * 8 + 0)) & 1u) ? 0x3F80u : 0u) | (((w >> (c * 8 + 1)) & 1u) ? 0x3F800000u : 0u);
                qv.y = (((w >> (c * 8 + 2)) & 1u) ? 0x3F80u : 0u) | (((w >> (c * 8 + 3)) & 1u) ? 0x3F800000u : 0u);
                qv.z = (((w >> (c * 8 + 4)) & 1u) ? 0x3F80u : 0u) | (((w >> (c * 8 + 5)) & 1u) ? 0x3F800000u : 0u);
                qv.w = (((w >> (c * 8 + 6)) & 1u) ? 0x3F80u : 0u) | (((w >> (c * 8 + 7)) & 1u) ? 0x3F800000u : 0u);
                int chunk = (awsel * 4 + c) ^ (arow & 7);
                *(uint4*)(adst + chunk * 16) = qv;
            }
        }
        __syncthreads();
        mfma_phase2(Aexp, Bhi, Blo, wm, wn, lane, acc);
        __syncthreads();
    }
    // ---- fused header-info tiles: 2 x K=64 over rel^T x infoT planes ----
    #pragma unroll
    for (int kt = 0; kt < 2; kt++) {
        const unsigned short* ih_b = ihiT + ((long)b * DIM + n0) * 128 + kt * 64;
        const unsigned short* il_b = iloT + ((long)b * DIM + n0) * 128 + kt * 64;
        GLD(ih_b + io0, Bhi + lb0); GLD(ih_b + io1, Bhi + lb1);
        GLD(ih_b + io2, Bhi + lb2); GLD(ih_b + io3, Bhi + lb3);
        GLD(il_b + io0, Blo + lb0); GLD(il_b + io1, Blo + lb1);
        GLD(il_b + io2, Blo + lb2); GLD(il_b + io3, Blo + lb3);
        const int* relrow = (kt ? rel_cd : rel_rd) + ((long)b * 64 + lane) * ND + m0 + wid * 32;
        #pragma unroll
        for (int c4 = 0; c4 < 32; c4 += 4) {
            int4 v = *(const int4*)(relrow + c4);
            unsigned long long mm;
            mm = __ballot(v.x != 0);
            if ((lane >> 1) == c4 + 0) LDSw[(wid * 32 + c4 + 0) * 2 + (lane & 1)] = (unsigned)(mm >> ((lane & 1) * 32));
            mm = __ballot(v.y != 0);
            if ((lane >> 1) == c4 + 1) LDSw[(wid * 32 + c4 + 1) * 2 + (lane & 1)] = (unsigned)(mm >> ((lane & 1) * 32));
            mm = __ballot(v.z != 0);
            if ((lane >> 1) == c4 + 2) LDSw[(wid * 32 + c4 + 2) * 2 + (lane & 1)] = (unsigned)(mm >> ((lane & 1) * 32));
            mm = __ballot(v.w != 0);
            if ((lane >> 1) == c4 + 3) LDSw[(wid * 32 + c4 + 3) * 2 + (lane & 1)] = (unsigned)(mm >> ((lane & 1) * 32));
        }
        __syncthreads();
        {
            unsigned w = LDSw[arow * 2 + awsel];
            unsigned dv = (unsigned)dmu[arow];
            unsigned dvh = dv << 16;
            #pragma unroll
            for (int c = 0; c < 4; c++) {
                uint4 qv;
                qv.x = (((w >> (c * 8 + 0)) & 1u) ? dv : 0u) | (((w >> (c * 8 + 1)) & 1u) ? dvh : 0u);
                qv.y = (((w >> (c * 8 + 2)) & 1u) ? dv : 0u) | (((w >> (c * 8 + 3)) & 1u) ? dvh : 0u);
                qv.z = (((w >> (c * 8 + 4)) & 1u) ? dv : 0u) | (((w >> (c * 8 + 5)) & 1u) ? dvh : 0u);
                qv.w = (((w >> (c * 8 + 6)) & 1u) ? dv : 0u) | (((w >> (c * 8 + 7)) & 1u) ? dvh : 0u);
                int chunk = (awsel * 4 + c) ^ (arow & 7);
                *(uint4*)(adst + chunk * 16) = qv;
            }
        }
        __syncthreads();
        mfma_phase2(Aexp, Bhi, Blo, wm, wn, lane, acc);
        __syncthreads();
    }
    // ---- epilogue ----
    #pragma unroll
    for (int mi = 0; mi < 4; mi++) {
        int grow = m0 + wm * 64 + mi * 16 + (lane >> 4) * 4;
        float inv[4];
        #pragma unroll
        for (int r = 0; r < 4; r++) inv[r] = 1.f / rownum[(long)b * ND + grow + r];
        #pragma unroll
        for (int ni = 0; ni < 4; ni++) {
            int gcol = n0 + wn * 64 + ni * 16 + (lane & 15);
            #pragma unroll
            for (int r = 0; r < 4; r++) {
                long off = ((long)b * ND + grow + r) * DIM + gcol;
                out[off] = fmaxf(acc[mi][ni][r] * inv[r], 0.f);
            }
        }
    }
}

// ==================================================================================
extern "C" void kernel_launch(void* const* d_in, const int* in_sizes, int n_in,
                              void* d_out, int out_size, void* d_ws, size_t ws_size,
                              hipStream_t stream)
{
    const float* q       = (const float*)d_in[0];
    const float* rh0     = (const float*)d_in[1];
    const float* ch0     = (const float*)d_in[2];
    const float* dc0     = (const float*)d_in[3];
    const int*   rm      = (const int*)d_in[4];
    const int*   cm      = (const int*)d_in[5];
    const int*   dmask   = (const int*)d_in[6];
    const int*   same_row= (const int*)d_in[7];
    const int*   same_col= (const int*)d_in[8];
    const int*   rel_rd  = (const int*)d_in[9];
    const int*   rel_cd  = (const int*)d_in[10];
    const float* wnode   = (const float*)d_in[11];
    const float* w_rdc   = (const float*)d_in[12];
    const float* w_cdc   = (const float*)d_in[13];
    const float* w_dcr   = (const float*)d_in[14];
    const float* w_dcc   = (const float*)d_in[15];
    const float* w_sr    = (const float*)d_in[16];
    const float* w_rq    = (const float*)d_in[18];
    const float* w_cq    = (const float*)d_in[19];

    float* out = (float*)d_out;
    float* rh = out;                           // [16,64,512]
    float* ch = out + (long)NB * NR * DIM;     // [16,64,512]
    float* dc = out + (long)NB * NR * DIM * 2; // [16,2048,512]

    if (ws_size < (size_t)WS_FLOATS * 4) return;

    float* ws      = (float*)d_ws;
    float* rh_num  = ws + OFF_RHNUM;
    float* ch_num  = ws + OFF_CHNUM;
    float* dc_num  = ws + OFF_DCNUM;
    float* qrow    = ws + OFF_QROW;
    float* qcol    = ws + OFF_QCOL;
    float* pre_r   = ws + OFF_PRER;
    float* pre_c   = ws + OFF_PREC;
    unsigned short* ihiT = (unsigned short*)(ws + OFF_INFORC);  // [16][512][128]
    unsigned short* iloT = ihiT + (size_t)NB * DIM * 128;
    unsigned* bits = (unsigned*)(ws + OFF_BITS);
    unsigned short* dhi = (unsigned short*)(ws + OFF_DCS);
    unsigned short* dlo = dhi + (size_t)NB * ND * DIM;
    unsigned short* thi = (unsigned short*)(ws + OFF_PROJ);  // transposed dcs planes
    unsigned short* tlo = thi + (size_t)NB * DIM * ND;
    unsigned short* phi = (unsigned short*)(ws + OFF_PROJ);  // proj planes overwrite thi/tlo (dead)
    unsigned short* plo = phi + (size_t)NB * DIM * ND;
    // whi/wlo in out-dc slice (dead between k_split-read and k_agg_final-write)
    unsigned short* whi = (unsigned short*)dc;
    unsigned short* wlo = whi + (size_t)DIM * DIM;

    hipMemcpyAsync(rh, rh0, sizeof(float) * (size_t)NB * NR * DIM, hipMemcpyDeviceToDevice, stream);
    hipMemcpyAsync(ch, ch0, sizeof(float) * (size_t)NB * NCOL * DIM, hipMemcpyDeviceToDevice, stream);

    k_bits<<<NB * ND / 2, 256, 0, stream>>>(same_row, same_col, dmask, bits, dc_num);
    k_rcnum<<<512, 256, 0, stream>>>(rel_rd, rel_cd, rm, cm, dmask, rh_num, ch_num);
    k_dcnum_final<<<dim3(ND / 256, NB), 256, 0, stream>>>(rel_rd, rel_cd, rm, cm, dmask, dc_num);
    k_q<<<dim3(128, 2, NB), 256, 0, stream>>>(q, w_rq, w_cq, qrow, qcol);

    for (int it = 0; it < 2; it++) {
        k_split<<<dim3(128, NB), 256, 0, stream>>>(it == 0 ? dc0 : dc, wnode, dmask, dhi, dlo, thi, tlo);
        k_wsplit<<<128, 256, 0, stream>>>(w_sr, whi, wlo);
        gemm_info2<<<dim3(8, 2, NB), 256, 0, stream>>>(rh, ch, w_dcr, w_dcc, rm, cm, wnode, ihiT, iloT);
        k_pre_rc_mfma<<<dim3(8, NB), 256, 0, stream>>>(rel_rd, rel_cd, thi, tlo, rm, cm, pre_r, pre_c);
        k_proj_mfma<<<1024, 256, 0, stream>>>(whi, wlo, dhi, dlo, phi, plo);
        gemm_head2<<<dim3(8, 2, NB), 256, 0, stream>>>(pre_r, pre_c, w_rdc, w_cdc,
            rh, ch, rm, cm, qrow, qcol, rh_num, ch_num);
        k_agg_final<<<1024, 256, 0, stream>>>(bits, phi, plo, ihiT, iloT,
            rel_rd, rel_cd, dmask, dc_num, dc);
    }
}